// Round 15
// baseline (695.763 us; speedup 1.0000x reference)
//
#include <hip/hip_runtime.h>
#include <math.h>

typedef unsigned short ushort;
typedef __attribute__((ext_vector_type(4))) unsigned short bfx4;
typedef __attribute__((ext_vector_type(8))) short short8;
typedef __attribute__((ext_vector_type(8))) unsigned short ushort8;
typedef __attribute__((ext_vector_type(4))) float f32x4;
typedef unsigned int u32;

#define VM_WAIT(N) asm volatile("s_waitcnt vmcnt(" #N ")" ::: "memory")
#define SBAR() asm volatile("s_barrier" ::: "memory")

__device__ __forceinline__ int swz4(int row) {
  return (row & 3) ^ ((row >> 2) & 3);
}

__device__ __forceinline__ ushort f2bf(float f) {
  u32 u = __float_as_uint(f);
  return (ushort)((u + 0x7FFF + ((u >> 16) & 1)) >> 16);
}
__device__ __forceinline__ float bf2f(ushort u) {
  u32 v = ((u32)u) << 16;
  return __uint_as_float(v);
}

__device__ __forceinline__ void gload16(const void* g, void* l) {
  __builtin_amdgcn_global_load_lds(
      (const __attribute__((address_space(1))) u32*)g,
      (__attribute__((address_space(3))) u32*)l, 16, 0, 0);
}

// ---------------- fp32 VALU GEMM (static Wf GEMMs only), z=which -------------
#define BKK 32
#define LDSP 68
__global__ __launch_bounds__(256) void gemm_generic(
    const float* __restrict__ A, const float* __restrict__ Bm, const float* __restrict__ Bm2,
    float* __restrict__ C, float* __restrict__ C2,
    int M, int N, int K, long sAi, long sAk, long sBj, long sBk, long sCi)
{
  __shared__ __align__(16) float lds_a[BKK * LDSP];
  __shared__ __align__(16) float lds_b[BKK * LDSP];
  const float* Bb = blockIdx.z ? Bm2 : Bm;
  float* Cc = blockIdx.z ? C2 : C;
  const int i0 = blockIdx.y * 64;
  const int j0 = blockIdx.x * 64;
  const int tid = threadIdx.x;
  const int tx = tid & 15, ty = tid >> 4;
  float acc[4][4] = {};
  for (int k0 = 0; k0 < K; k0 += BKK) {
    for (int idx = tid; idx < BKK * 64; idx += 256) {
      int kk = idx & (BKK - 1), ii = idx >> 5;
      int gi = i0 + ii, gk = k0 + kk;
      lds_a[kk * LDSP + ii] = (gi < M && gk < K) ? A[(long)gi * sAi + (long)gk * sAk] : 0.f;
    }
    for (int idx = tid; idx < BKK * 64; idx += 256) {
      int kk = idx & (BKK - 1), jj = idx >> 5;
      int gj = j0 + jj, gk = k0 + kk;
      lds_b[kk * LDSP + jj] = (gj < N && gk < K) ? Bb[(long)gj * sBj + (long)gk * sBk] : 0.f;
    }
    __syncthreads();
    #pragma unroll
    for (int kk = 0; kk < BKK; ++kk) {
      const float4 a4 = *reinterpret_cast<const float4*>(&lds_a[kk * LDSP + ty * 4]);
      const float4 b4 = *reinterpret_cast<const float4*>(&lds_b[kk * LDSP + tx * 4]);
      const float av[4] = {a4.x, a4.y, a4.z, a4.w};
      const float bv[4] = {b4.x, b4.y, b4.z, b4.w};
      #pragma unroll
      for (int a = 0; a < 4; ++a)
        #pragma unroll
        for (int b = 0; b < 4; ++b)
          acc[a][b] = fmaf(av[a], bv[b], acc[a][b]);
    }
    __syncthreads();
  }
  for (int a = 0; a < 4; ++a) {
    int gi = i0 + ty * 4 + a;
    if (gi >= M) continue;
    for (int b = 0; b < 4; ++b) {
      int gj = j0 + tx * 4 + b;
      if (gj >= N) continue;
      Cc[(long)gi * sCi + gj] = acc[a][b];
    }
  }
}

// ---------------- merged k GEMM: 128x128 tile, bf16 out, z=which -------------
__global__ __launch_bounds__(256) void mfma_gemm(
    const ushort* __restrict__ A0, const ushort* __restrict__ A1,
    const ushort* __restrict__ B0, const ushort* __restrict__ B1,
    const float* __restrict__ bias0, const float* __restrict__ bias1,
    ushort* __restrict__ C0, ushort* __restrict__ C1,
    int M, int N, int K, long sAi, long sBj, long sCi)
{
  __shared__ ushort As[128 * 64];
  __shared__ ushort Bs[128 * 64];
  const int which = blockIdx.z;
  const ushort* Ab = which ? A1 : A0;
  const ushort* Bb = which ? B1 : B0;
  const float* bias = which ? bias1 : bias0;
  ushort* C = which ? C1 : C0;
  const int i0 = blockIdx.y * 128;
  const int j0 = blockIdx.x * 128;
  const int tid = threadIdx.x;
  const int wave = tid >> 6, lane = tid & 63;
  const int wm = wave >> 1, wn = wave & 1;
  const int col16 = lane & 15, krow = lane >> 4;

  f32x4 acc[4][4] = {};

  for (int k0 = 0; k0 < K; k0 += 64) {
    #pragma unroll
    for (int it = 0; it < 4; ++it) {
      int chunk = it * 256 + wave * 64 + lane;
      int row = chunk >> 3, s = chunk & 7;
      int kc = s ^ (row & 7);
      int gi = i0 + row; if (gi >= M) gi = M - 1;
      gload16(Ab + (long)gi * sAi + k0 + kc * 8, &As[chunk * 8]);
    }
    #pragma unroll
    for (int it = 0; it < 4; ++it) {
      int chunk = it * 256 + wave * 64 + lane;
      int row = chunk >> 3, s = chunk & 7;
      int kc = s ^ (row & 7);
      int gj = j0 + row; if (gj >= N) gj = N - 1;
      gload16(Bb + (long)gj * sBj + k0 + kc * 8, &Bs[chunk * 8]);
    }
    __syncthreads();
    #pragma unroll
    for (int ks = 0; ks < 2; ++ks) {
      short8 af[4], bfr[4];
      #pragma unroll
      for (int mi = 0; mi < 4; ++mi) {
        int row = wm * 64 + mi * 16 + col16;
        int slot = (ks * 4 + krow) ^ (row & 7);
        af[mi] = *(const short8*)&As[row * 64 + slot * 8];
      }
      #pragma unroll
      for (int nj = 0; nj < 4; ++nj) {
        int row = wn * 64 + nj * 16 + col16;
        int slot = (ks * 4 + krow) ^ (row & 7);
        bfr[nj] = *(const short8*)&Bs[row * 64 + slot * 8];
      }
      #pragma unroll
      for (int mi = 0; mi < 4; ++mi)
        #pragma unroll
        for (int nj = 0; nj < 4; ++nj)
          acc[mi][nj] = __builtin_amdgcn_mfma_f32_16x16x32_bf16(
              af[mi], bfr[nj], acc[mi][nj], 0, 0, 0);
    }
    __syncthreads();
  }

  const int r0 = krow * 4;
  #pragma unroll
  for (int mi = 0; mi < 4; ++mi) {
    int gi0 = i0 + wm * 64 + mi * 16 + r0;
    #pragma unroll
    for (int nj = 0; nj < 4; ++nj) {
      int gj = j0 + wn * 64 + nj * 16 + col16;
      f32x4 a = acc[mi][nj];
      #pragma unroll
      for (int r = 0; r < 4; ++r) {
        int gi = gi0 + r;
        if (gi >= M || gj >= N) continue;
        C[(long)gi * sCi + gj] = f2bf(a[r] + bias[gj]);
      }
    }
  }
}

// ---------------- transpose k (bf16): per batch [96][197]-view -> [197][128] -
__global__ __launch_bounds__(256) void transpose_k(
    const ushort* __restrict__ k1, const ushort* __restrict__ k2,
    ushort* __restrict__ EA1, ushort* __restrict__ EA2, int Bc)
{
  __shared__ ushort tile[32][33];
  int z = blockIdx.z;
  int which = (z >= Bc) ? 1 : 0;
  int b = which ? z - Bc : z;
  const ushort* src = (which ? k2 : k1) + (long)b * 18912;
  ushort* dst = (which ? EA2 : EA1) + (long)b * 25216;
  int l0 = blockIdx.x * 32, c0 = blockIdx.y * 32;
  int tx = threadIdx.x & 31, ty = threadIdx.x >> 5;
  for (int r = ty; r < 32; r += 8) {
    int c = c0 + r, l = l0 + tx;
    tile[r][tx] = (c < 96 && l < 197) ? src[(long)c * 197 + l] : (ushort)0;
  }
  __syncthreads();
  for (int r = ty; r < 32; r += 8) {
    int l = l0 + r, c = c0 + tx;
    if (l < 197 && c < 128) dst[(long)l * 128 + c] = tile[tx][r];
  }
}

// ---------------- energy GEMM (MFMA): E = EA1 . EA2^T, dual bf16 write -------
__global__ __launch_bounds__(256) void energy_mfma(
    const ushort* __restrict__ EA1, const ushort* __restrict__ EA2,
    ushort* __restrict__ Eb, ushort* __restrict__ ETb)
{
  __shared__ ushort elds[16896];     // staging 2x8192; bounce [128][132]
  ushort* As = elds;
  ushort* Bs = elds + 8192;
  const int bz = blockIdx.z;
  const ushort* Ab = EA1 + 25216L * bz;
  const ushort* Bb = EA2 + 25216L * bz;
  const int i0 = blockIdx.y * 128;   // l
  const int j0 = blockIdx.x * 128;   // m
  const int tid = threadIdx.x;
  const int wave = tid >> 6, lane = tid & 63;
  const int wm = wave >> 1, wn = wave & 1;
  const int col16 = lane & 15, krow = lane >> 4;

  f32x4 acc[4][4] = {};

  for (int k0 = 0; k0 < 128; k0 += 64) {
    #pragma unroll
    for (int it = 0; it < 4; ++it) {
      int chunk = it * 256 + wave * 64 + lane;
      int row = chunk >> 3, s = chunk & 7;
      int kc = s ^ (row & 7);
      int gi = i0 + row; if (gi > 196) gi = 196;
      gload16(Ab + (long)gi * 128 + k0 + kc * 8, &As[chunk * 8]);
    }
    #pragma unroll
    for (int it = 0; it < 4; ++it) {
      int chunk = it * 256 + wave * 64 + lane;
      int row = chunk >> 3, s = chunk & 7;
      int kc = s ^ (row & 7);
      int gj = j0 + row; if (gj > 196) gj = 196;
      gload16(Bb + (long)gj * 128 + k0 + kc * 8, &Bs[chunk * 8]);
    }
    __syncthreads();
    #pragma unroll
    for (int ks = 0; ks < 2; ++ks) {
      short8 af[4], bfr[4];
      #pragma unroll
      for (int mi = 0; mi < 4; ++mi) {
        int row = wm * 64 + mi * 16 + col16;
        int slot = (ks * 4 + krow) ^ (row & 7);
        af[mi] = *(const short8*)&As[row * 64 + slot * 8];
      }
      #pragma unroll
      for (int nj = 0; nj < 4; ++nj) {
        int row = wn * 64 + nj * 16 + col16;
        int slot = (ks * 4 + krow) ^ (row & 7);
        bfr[nj] = *(const short8*)&Bs[row * 64 + slot * 8];
      }
      #pragma unroll
      for (int mi = 0; mi < 4; ++mi)
        #pragma unroll
        for (int nj = 0; nj < 4; ++nj)
          acc[mi][nj] = __builtin_amdgcn_mfma_f32_16x16x32_bf16(
              af[mi], bfr[nj], acc[mi][nj], 0, 0, 0);
    }
    __syncthreads();
  }

  ushort* obufT = elds;
  #pragma unroll
  for (int mi = 0; mi < 4; ++mi)
    #pragma unroll
    for (int nj = 0; nj < 4; ++nj) {
      int mcol = wn * 64 + nj * 16 + col16;
      int lrow = wm * 64 + mi * 16 + krow * 4;
      bfx4 h;
      #pragma unroll
      for (int r = 0; r < 4; ++r) h[r] = f2bf(acc[mi][nj][r]);
      *(bfx4*)&obufT[mcol * 132 + lrow] = h;
    }
  SBAR();
  {
    int lL = tid & 63, mg = tid >> 6;
    for (int it = 0; it < 32; ++it) {
      int mL = mg * 32 + it;
      int gm = j0 + mL;
      if (gm >= 197) break;
      #pragma unroll
      for (int lh = 0; lh < 2; ++lh) {
        int l = lh * 64 + lL;
        int gl = i0 + l;
        if (gl < 224)
          ETb[bz * 50432L + (long)gm * 256 + gl] =
              (gl < 197) ? obufT[mL * 132 + l] : (ushort)0;
      }
    }
  }
  {
    int mL = tid & 63, lg = tid >> 6;
    for (int it = 0; it < 32; ++it) {
      int lL = lg * 32 + it;
      int gl = i0 + lL;
      if (gl >= 197) break;
      #pragma unroll
      for (int mh = 0; mh < 2; ++mh) {
        int m = mh * 64 + mL;
        int gm = j0 + m;
        if (gm < 224)
          Eb[bz * 50432L + (long)gl * 256 + gm] =
              (gm < 197) ? obufT[m * 132 + lL] : (ushort)0;
      }
    }
  }
}

// ---------------- flat v GEMM: 256 thr, 128x128 tile, hoisted addrs ----------
// lds layout: A buf0 @0, A buf1 @8192, B buf0 @16384, B buf1 @24576 (bytes).
__global__ __launch_bounds__(256) void vbig_gemm(
    const ushort* __restrict__ A0, const ushort* __restrict__ A1,
    const ushort* __restrict__ B0, const ushort* __restrict__ B1,
    const float* __restrict__ bias0, const float* __restrict__ bias1,
    ushort* __restrict__ C0, ushort* __restrict__ C1,
    int ntiles, long Nc)
{
  __shared__ ushort lds[16384];        // 32 KB
  const int per = 6 * ntiles;
  int bid = blockIdx.x;
  const int which = bid / per;
  bid -= which * per;
  int mtile, ntile;
  if ((ntiles & 7) == 0) {
    int xcd = bid & 7;
    int grp = bid >> 3;
    mtile = grp % 6;
    ntile = (grp / 6) * 8 + xcd;       // same-(sblk,xcd) blocks share B panel
  } else {
    ntile = bid % ntiles;
    mtile = bid / ntiles;
  }
  const ushort* Ab = (which ? A1 : A0) + (long)(mtile * 128) * 768;
  const ushort* Bb = which ? B1 : B0;
  const float* bias = which ? bias1 : bias0;
  ushort* C = which ? C1 : C0;
  const int n0 = ntile * 128;
  const int tid = threadIdx.x, wave = tid >> 6, lane = tid & 63;
  const int wm = wave >> 1, wn = wave & 1;   // 2x2 wave grid: 64 x 64 tiles
  const int col16 = lane & 15, kq = lane >> 4;

  f32x4 acc[4][4] = {};

  // hoisted stage addressing: wave w owns chunks {4w..4w+3}
  const ushort* gsrc[4];
  int dst0[4];
  {
    const int lrow = lane >> 2, s = lane & 3;
    #pragma unroll
    for (int c0 = 0; c0 < 4; ++c0) {
      int c = wave * 4 + c0;
      if (c < 8) {
        int row = c * 16 + lrow;
        int kc = s ^ swz4(row);
        gsrc[c0] = Ab + (long)row * 768 + kc * 8;
        dst0[c0] = c * 1024 + lane * 16;
      } else {
        int j = (c - 8) * 16 + lrow;
        int n = n0 + j;
        int b = n / 224;
        int l = n - b * 224;
        int grow = b * 197 + (l < 197 ? l : 196);
        int kc = s ^ swz4(j);
        gsrc[c0] = Bb + (long)grow * 768 + kc * 8;
        dst0[c0] = 16384 + (c - 8) * 1024 + lane * 16;
      }
    }
  }
  // hoisted ds_read byte offsets (buf0); +8192 for buf1
  int aoff[4], boff[4];
  #pragma unroll
  for (int mi = 0; mi < 4; ++mi) {
    int arow = wm * 64 + mi * 16 + col16;
    aoff[mi] = arow * 64 + ((kq ^ swz4(arow)) << 4);
  }
  #pragma unroll
  for (int nj = 0; nj < 4; ++nj) {
    int brow = wn * 64 + nj * 16 + col16;
    boff[nj] = 16384 + brow * 64 + ((kq ^ swz4(brow)) << 4);
  }

  #define VB_STAGE(BUF, K0)                                            \
    { _Pragma("unroll")                                                \
      for (int c0 = 0; c0 < 4; ++c0)                                   \
        gload16(gsrc[c0] + (K0), (char*)lds + dst0[c0] + (BUF) * 8192); }
  #define VB_COMPUTE(BUF)                                              \
    { short8 af[4], bfr[4];                                            \
      _Pragma("unroll")                                                \
      for (int mi = 0; mi < 4; ++mi)                                   \
        af[mi] = *(const short8*)((const char*)lds + aoff[mi] + (BUF) * 8192); \
      _Pragma("unroll")                                                \
      for (int nj = 0; nj < 4; ++nj)                                   \
        bfr[nj] = *(const short8*)((const char*)lds + boff[nj] + (BUF) * 8192); \
      _Pragma("unroll")                                                \
      for (int mi = 0; mi < 4; ++mi)                                   \
        _Pragma("unroll")                                              \
        for (int nj = 0; nj < 4; ++nj)                                 \
          acc[mi][nj] = __builtin_amdgcn_mfma_f32_16x16x32_bf16(       \
              af[mi], bfr[nj], acc[mi][nj], 0, 0, 0); }

  VB_STAGE(0, 0);
  #pragma unroll 1
  for (int k = 32; k <= 736; k += 64) {
    VB_STAGE(1, k);
    VM_WAIT(4);
    SBAR();
    VB_COMPUTE(0);
    SBAR();
    if (k + 32 < 768) {
      VB_STAGE(0, k + 32);
      VM_WAIT(4);
    } else {
      VM_WAIT(0);
    }
    SBAR();
    VB_COMPUTE(1);
    SBAR();
  }
  #undef VB_STAGE
  #undef VB_COMPUTE

  #pragma unroll
  for (int mi = 0; mi < 4; ++mi) {
    #pragma unroll
    for (int r = 0; r < 4; ++r) {
      int gi = mtile * 128 + wm * 64 + mi * 16 + kq * 4 + r;
      float bv = bias[gi];
      long base = (long)gi * Nc;
      #pragma unroll
      for (int nj = 0; nj < 4; ++nj) {
        int n = n0 + wn * 64 + nj * 16 + col16;
        int b = n / 224;
        int l = n - b * 224;
        C[base + n] = (l < 197) ? f2bf(acc[mi][nj][r] + bv) : (ushort)0;
      }
    }
  }
}

// ---------------- fused att-logit GEMM + column softmax, counted vmcnt -------
__global__ __launch_bounds__(256) void att_gemm(
    const ushort* __restrict__ Wl0, const ushort* __restrict__ Wl1,
    const ushort* __restrict__ E0, const ushort* __restrict__ E1,
    const float* __restrict__ bl0, const float* __restrict__ bl1,
    ushort* __restrict__ a0, ushort* __restrict__ a1out)
{
  __shared__ ushort Aws[2][208 * 32];
  __shared__ ushort Bws[2][64 * 32];
  __shared__ float blds[208];
  const int which = blockIdx.z;
  const int bz = blockIdx.y;
  const ushort* Wl = which ? Wl1 : Wl0;
  const ushort* Bb = (which ? E1 : E0) + 50432L * bz;
  const float* bl = which ? bl1 : bl0;
  ushort* aout = which ? a1out : a0;
  const int l0 = blockIdx.x * 64;
  const int tid = threadIdx.x, wave = tid >> 6, lane = tid & 63;
  const int col16 = lane & 15, kq = lane >> 4;

  if (tid < 208) blds[tid] = (tid < 197) ? bl[tid] : 0.f;

  f32x4 acc[13] = {};

  auto stage = [&](int buf, int k0) {
    const int lrow = lane >> 2, s = lane & 3;
    #pragma unroll
    for (int c0 = 0; c0 < 5; ++c0) {
      int c = wave + c0 * 4;
      if (c >= 17) break;
      if (c < 13) {
        int row = c * 16 + lrow;
        int gr = row < 197 ? row : 196;
        int kc = s ^ swz4(row);
        gload16(Wl + (long)gr * 256 + k0 + kc * 8,
                (char*)(&Aws[buf][0]) + c * 1024 + lane * 16);
      } else {
        int row = (c - 13) * 16 + lrow;
        int gl = l0 + row; if (gl > 196) gl = 196;
        int kc = s ^ swz4(row);
        gload16(Bb + (long)gl * 256 + k0 + kc * 8,
                (char*)(&Bws[buf][0]) + (c - 13) * 1024 + lane * 16);
      }
    }
  };

  stage(0, 0);
  for (int t = 0; t < 7; ++t) {
    int cur = t & 1;
    if (t + 1 < 7) {
      stage(cur ^ 1, (t + 1) * 32);
      if (wave == 0) VM_WAIT(5); else VM_WAIT(4);
    } else {
      VM_WAIT(0);
    }
    SBAR();
    int brow = wave * 16 + col16;
    short8 bf = *(const short8*)((const char*)(&Bws[cur][0]) +
                                 brow * 64 + ((kq ^ swz4(brow)) << 4));
    #pragma unroll
    for (int j = 0; j < 13; ++j) {
      int arow = j * 16 + col16;
      short8 af = *(const short8*)((const char*)(&Aws[cur][0]) +
                                   arow * 64 + ((kq ^ swz4(arow)) << 4));
      acc[j] = __builtin_amdgcn_mfma_f32_16x16x32_bf16(af, bf, acc[j], 0, 0, 0);
    }
    SBAR();
  }

  const int c = l0 + wave * 16 + col16;
  float mx = -INFINITY;
  #pragma unroll
  for (int j = 0; j < 13; ++j)
    #pragma unroll
    for (int r = 0; r < 4; ++r) {
      int m = j * 16 + kq * 4 + r;
      float v = acc[j][r] + blds[m];
      v = (m < 197) ? v : -INFINITY;
      acc[j][r] = v;
      mx = fmaxf(mx, v);
    }
  mx = fmaxf(mx, __shfl_xor(mx, 16));
  mx = fmaxf(mx, __shfl_xor(mx, 32));
  float s = 0.f;
  #pragma unroll
  for (int j = 0; j < 13; ++j)
    #pragma unroll
    for (int r = 0; r < 4; ++r) {
      int m = j * 16 + kq * 4 + r;
      float e = (m < 197) ? __expf(acc[j][r] - mx) : 0.f;
      acc[j][r] = e;
      s += e;
    }
  s += __shfl_xor(s, 16);
  s += __shfl_xor(s, 32);
  const float inv = 1.f / s;
  ushort* ab = aout + 50432L * bz;
  #pragma unroll
  for (int j = 0; j < 13; ++j)
    #pragma unroll
    for (int r = 0; r < 4; ++r) {
      int m = j * 16 + kq * 4 + r;
      if (m < 197)
        ab[(long)m * 256 + c] = (c < 197) ? f2bf(acc[j][r] * inv) : (ushort)0;
    }
}

// ---------------- out GEMM: 512 thr, 128x224 tile, hoisted addrs, bounce-v2 --
__global__ __launch_bounds__(512) void vout_gemm(
    const ushort* __restrict__ A0, const ushort* __restrict__ A1,
    const ushort* __restrict__ B0, const ushort* __restrict__ B1,
    const ushort* __restrict__ resid0, const ushort* __restrict__ resid1,
    const float* __restrict__ g0, const float* __restrict__ g1,
    float* __restrict__ C0, float* __restrict__ C1,
    int N, int K, long sAi, long bAs, long sBj, long bBs,
    long sCi, long bCs, int mtiles, int batches)
{
  __shared__ ushort lds_all[22528];       // A dbuf 2x4096 | B dbuf 2x7168
  const int per = mtiles * batches;
  int bid = blockIdx.x;
  const int which = bid / per;
  bid -= which * per;
  const ushort* A = which ? A1 : A0;
  const ushort* Bm = which ? B1 : B0;
  const ushort* resid = which ? resid1 : resid0;
  const float* gammaPtr = which ? g1 : g0;
  float* C = which ? C1 : C0;

  int mtile, bz;
  if ((batches & 7) == 0) {
    int xcd = bid & 7, sid = bid >> 3;
    mtile = sid % mtiles;
    bz = (sid / mtiles) * 8 + xcd;
  } else {
    mtile = bid % mtiles;
    bz = bid / mtiles;
  }
  const ushort* Ab = A + bAs * bz + (long)(mtile * 128) * sAi;
  const ushort* Bb = Bm + bBs * bz;
  const int tid = threadIdx.x, wave = tid >> 6, lane = tid & 63;
  const int wr = wave >> 1, wc = wave & 1;    // 4x2 grid: 32 x 112 tiles
  const int col16 = lane & 15, kq = lane >> 4;

  f32x4 acc[2][7] = {};

  // hoisted stage addressing: chunks c = wave + 8*c0; waves 0-5 -> 3, 6-7 -> 2
  const ushort* gsrc[3];
  int d0[3], d1[3];
  const int nch = (wave < 6) ? 3 : 2;
  {
    const int lrow = lane >> 2, s = lane & 3;
    #pragma unroll
    for (int c0 = 0; c0 < 3; ++c0) {
      int c = wave + c0 * 8;
      if (c >= 22) break;
      if (c < 8) {
        int row = c * 16 + lrow;
        int kc = s ^ swz4(row);
        gsrc[c0] = Ab + (long)row * sAi + kc * 8;
        d0[c0] = c * 1024 + lane * 16;
        d1[c0] = d0[c0] + 8192;
      } else {
        int row = (c - 8) * 16 + lrow;
        int gj = row < N ? row : N - 1;
        int kc = s ^ swz4(row);
        gsrc[c0] = Bb + (long)gj * sBj + kc * 8;
        d0[c0] = 16384 + (c - 8) * 1024 + lane * 16;
        d1[c0] = d0[c0] + 14336;
      }
    }
  }
  int a0o[2], b0o[7];
  #pragma unroll
  for (int mi = 0; mi < 2; ++mi) {
    int arow = wr * 32 + mi * 16 + col16;
    a0o[mi] = arow * 64 + ((kq ^ swz4(arow)) << 4);
  }
  #pragma unroll
  for (int nj = 0; nj < 7; ++nj) {
    int brow = wc * 112 + nj * 16 + col16;
    b0o[nj] = 16384 + brow * 64 + ((kq ^ swz4(brow)) << 4);
  }

  auto stage = [&](int buf, int k0) {
    #pragma unroll
    for (int c0 = 0; c0 < 3; ++c0) {
      if (c0 >= nch) break;                 // wave-uniform
      gload16(gsrc[c0] + k0, (char*)lds_all + (buf ? d1[c0] : d0[c0]));
    }
  };

  const int nt = K >> 5;
  stage(0, 0);
  for (int t = 0; t < nt; ++t) {
    int cur = t & 1;
    if (t + 1 < nt) {
      stage(cur ^ 1, (t + 1) << 5);
      if (wave < 6) VM_WAIT(3); else VM_WAIT(2);
    } else {
      VM_WAIT(0);
    }
    SBAR();
    const int ab2 = cur * 8192, bb2 = cur * 14336;
    short8 af[2];
    #pragma unroll
    for (int mi = 0; mi < 2; ++mi)
      af[mi] = *(const short8*)((const char*)lds_all + a0o[mi] + ab2);
    #pragma unroll
    for (int nj = 0; nj < 7; ++nj) {
      short8 bf = *(const short8*)((const char*)lds_all + b0o[nj] + bb2);
      #pragma unroll
      for (int mi = 0; mi < 2; ++mi)
        acc[mi][nj] = __builtin_amdgcn_mfma_f32_16x16x32_bf16(
            af[mi], bf, acc[mi][nj], 0, 0, 0);
    }
    SBAR();
  }

  // bounce-v2: obufT [112 cols][132 rows] bf16, parallel dump per col-chunk.
  const float g = gammaPtr[0];
  ushort* obufT = lds_all;
  #pragma unroll 1
  for (int c = 0; c < 2; ++c) {
    if (wc == c) {
      #pragma unroll
      for (int mi = 0; mi < 2; ++mi)
        #pragma unroll
        for (int nj = 0; nj < 7; ++nj) {
          int colL = nj * 16 + col16;
          int row = wr * 32 + mi * 16 + kq * 4;
          bfx4 h;
          #pragma unroll
          for (int r = 0; r < 4; ++r) h[r] = f2bf(g * acc[mi][nj][r]);
          *(bfx4*)&obufT[colL * 132 + row] = h;
        }
    }
    SBAR();
    {
      int colL = tid & 127, rg = tid >> 7;
      int ncols = 197 - c * 112; if (ncols > 112) ncols = 112;
      if (colL < ncols) {
        int gcol = c * 112 + colL;
        #pragma unroll 4
        for (int it = 0; it < 32; ++it) {
          int row = rg * 32 + it;
          long ci = bCs * bz + (long)(mtile * 128 + row) * 197 + gcol;
          C[ci] = bf2f(obufT[colL * 132 + row]) + bf2f(resid[ci]);
        }
      }
    }
    SBAR();
  }
}

// ---------------- merged small helpers ---------------------------------------
__global__ void fuse_bias2(const float* __restrict__ Wks,
                           const float* __restrict__ bk1, const float* __restrict__ bk2,
                           const float* __restrict__ bks,
                           float* __restrict__ bf1, float* __restrict__ bf2) {
  int c = threadIdx.x;
  if (c >= 192) return;
  const float* bk = (c < 96) ? bk1 : bk2;
  float* bf = (c < 96) ? bf1 : bf2;
  int cc = (c < 96) ? c : c - 96;
  float s = bks[cc];
  for (int e = 0; e < 96; ++e) s += Wks[cc * 96 + e] * bk[e];
  bf[cc] = s;
}

__global__ __launch_bounds__(256) void conv_weights(
    const float* __restrict__ Wf1, const float* __restrict__ Wf2,
    const float* __restrict__ Wv1, const float* __restrict__ Wv2,
    const float* __restrict__ Wl1, const float* __restrict__ Wl2,
    ushort* __restrict__ Wf1b, ushort* __restrict__ Wf2b,
    ushort* __restrict__ Wv1b, ushort* __restrict__ Wv2b,
    ushort* __restrict__ Wl1b, ushort* __restrict__ Wl2b)
{
  const long total = 147456 + 1179648 + 100864;
  long stride = (long)gridDim.x * blockDim.x;
  for (long i = (long)blockIdx.x * blockDim.x + threadIdx.x; i < total; i += stride) {
    if (i < 147456) {
      long j = i;
      if (j < 73728) Wf1b[j] = f2bf(Wf1[j]);
      else Wf2b[j - 73728] = f2bf(Wf2[j - 73728]);
    } else if (i < 147456 + 1179648) {
      long j = i - 147456;
      if (j < 589824) Wv1b[j] = f2bf(Wv1[j]);
      else Wv2b[j - 589824] = f2bf(Wv2[j - 589824]);
    } else {
      long j = i - 147456 - 1179648;
      int w2 = j >= 50432;
      if (w2) j -= 50432;
      int r = (int)(j >> 8), cc = (int)(j & 255);
      const float* s = w2 ? Wl2 : Wl1;
      ushort* d = w2 ? Wl2b : Wl1b;
      d[j] = (cc < 197) ? f2bf(s[(long)r * 197 + cc]) : (ushort)0;
    }
  }
}

__global__ __launch_bounds__(256) void conv_xy(const float* __restrict__ x,
                                               const float* __restrict__ y,
                                               ushort* __restrict__ xb,
                                               ushort* __restrict__ yb, long n8) {
  long i = (long)blockIdx.x * blockDim.x + threadIdx.x;
  long stride = (long)gridDim.x * blockDim.x;
  for (; i < 2 * n8; i += stride) {
    const float* s = (i < n8) ? x : y;
    ushort* d = (i < n8) ? xb : yb;
    long j = (i < n8) ? i : i - n8;
    float4 a = ((const float4*)s)[2 * j];
    float4 b = ((const float4*)s)[2 * j + 1];
    ushort8 o;
    o[0] = f2bf(a.x); o[1] = f2bf(a.y); o[2] = f2bf(a.z); o[3] = f2bf(a.w);
    o[4] = f2bf(b.x); o[5] = f2bf(b.y); o[6] = f2bf(b.z); o[7] = f2bf(b.w);
    *(ushort8*)&d[j * 8] = o;
  }
}

// ---------------- launcher ---------------------------------------------------
extern "C" void kernel_launch(void* const* d_in, const int* in_sizes, int n_in,
                              void* d_out, int out_size, void* d_ws, size_t ws_size,
                              hipStream_t stream) {
  const float* x   = (const float*)d_in[0];
  const float* y   = (const float*)d_in[1];
  const float* Wk1 = (const float*)d_in[2];
  const float* bk1 = (const float*)d_in[3];
  const float* Wk2 = (const float*)d_in[4];
  const float* bk2 = (const float*)d_in[5];
  const float* Wks = (const float*)d_in[6];
  const float* bks = (const float*)d_in[7];
  const float* Wl1 = (const float*)d_in[8];
  const float* bl1 = (const float*)d_in[9];
  const float* Wl2 = (const float*)d_in[10];
  const float* bl2 = (const float*)d_in[11];
  const float* Wv1 = (const float*)d_in[12];
  const float* bv1 = (const float*)d_in[13];
  const float* Wv2 = (const float*)d_in[14];
  const float* bv2 = (const float*)d_in[15];
  const float* gamma1 = (const float*)d_in[16];
  const float* gamma2 = (const float*)d_in[17];
  float* out = (float*)d_out;

  const int B = 256, L = 197, D = 768;
  const long LD = (long)L * D;     // 151296

  const size_t staticBytes = 3446784;
  const size_t perB = 605184 + 75648 + 100864 + 201728 + 201728 + 688128;
  int Bc = 256;
  while (Bc > 8 && staticBytes + (size_t)Bc * perB > ws_size) Bc >>= 1;

  char* p = (char*)d_ws;
  auto carve = [&](size_t bytes) { char* r = p; p += bytes; return r; };
  float*  Wf1   = (float*)carve(73728 * 4);
  float*  Wf2   = (float*)carve(73728 * 4);
  float*  bf1   = (float*)carve(512);
  float*  bf2   = (float*)carve(512);
  ushort* Wv1b  = (ushort*)carve(589824 * 2);
  ushort* Wv2b  = (ushort*)carve(589824 * 2);
  ushort* Wf1b  = (ushort*)carve(73728 * 2);
  ushort* Wf2b  = (ushort*)carve(73728 * 2);
  ushort* Wl1b  = (ushort*)carve(50432 * 2);
  ushort* Wl2b  = (ushort*)carve(50432 * 2);
  ushort* xb    = (ushort*)carve((size_t)Bc * LD * 2);
  ushort* yb    = (ushort*)carve((size_t)Bc * LD * 2);
  ushort* k1    = (ushort*)carve((size_t)Bc * 18912 * 2);
  ushort* k2    = (ushort*)carve((size_t)Bc * 18912 * 2);
  ushort* EA1   = (ushort*)carve((size_t)Bc * 25216 * 2);
  ushort* EA2   = (ushort*)carve((size_t)Bc * 25216 * 2);
  ushort* Eb    = (ushort*)carve((size_t)Bc * 50432 * 2);
  ushort* ETbuf = (ushort*)carve((size_t)Bc * 50432 * 2);
  ushort* a1    = (ushort*)carve((size_t)Bc * 50432 * 2);
  ushort* a2    = (ushort*)carve((size_t)Bc * 50432 * 2);
  const long Nc = (long)Bc * 224;
  ushort* vT    = (ushort*)carve((size_t)768 * Nc * 2);
  ushort* vT2   = (ushort*)carve((size_t)768 * Nc * 2);

  dim3 blk(256);

  gemm_generic<<<dim3(12, 2, 2), blk, 0, stream>>>(Wks, Wk1, Wk2, Wf1, Wf2,
      96, 768, 96, 96, 1, 1, 768, 768);
  fuse_bias2<<<1, 192, 0, stream>>>(Wks, bk1, bk2, bks, bf1, bf2);
  conv_weights<<<dim3(1024), blk, 0, stream>>>(Wf1, Wf2, Wv1, Wv2, Wl1, Wl2,
      Wf1b, Wf2b, Wv1b, Wv2b, Wl1b, Wl2b);

  for (int c0 = 0; c0 < B; c0 += Bc) {
    const float* xc = x + (long)c0 * LD;
    const float* yc = y + (long)c0 * LD;
    const int Mr = Bc * L;
    const int gym = (Mr + 127) / 128;

    conv_xy<<<dim3(2048), blk, 0, stream>>>(xc, yc, xb, yb, (long)Bc * LD / 8);

    mfma_gemm<<<dim3(1, gym, 2), blk, 0, stream>>>(xb, yb, Wf1b, Wf2b, bf1, bf2,
        k1, k2, Mr, 96, 768, 768, 768, 96);

    transpose_k<<<dim3(7, 4, 2 * Bc), blk, 0, stream>>>(k1, k2, EA1, EA2, Bc);

    energy_mfma<<<dim3(2, 2, Bc), blk, 0, stream>>>(EA1, EA2, Eb, ETbuf);

    att_gemm<<<dim3(4, Bc, 2), blk, 0, stream>>>(Wl1b, Wl2b, Eb, ETbuf,
        bl1, bl2, a1, a2);

    {
      int ntiles = (int)(Nc / 128);
      vbig_gemm<<<dim3(2 * 6 * ntiles), blk, 0, stream>>>(
          Wv2b, Wv1b, yb, xb, bv2, bv1, vT, vT2, ntiles, Nc);
    }

    vout_gemm<<<dim3(12 * Bc), dim3(512), 0, stream>>>(vT, vT2, a1, a2,
        xb, yb, gamma1, gamma2,
        out + (long)c0 * LD, out + (long)B * LD + (long)c0 * LD,
        197, 224, Nc, 224, 256, 50432, 197, LD, 6, Bc);
  }
}

// Round 16
// 662.384 us; speedup vs baseline: 1.0504x; 1.0504x over previous
//
#include <hip/hip_runtime.h>
#include <math.h>

typedef unsigned short ushort;
typedef __attribute__((ext_vector_type(4))) unsigned short bfx4;
typedef __attribute__((ext_vector_type(8))) short short8;
typedef __attribute__((ext_vector_type(8))) unsigned short ushort8;
typedef __attribute__((ext_vector_type(4))) float f32x4;
typedef unsigned int u32;

#define VM_WAIT(N) asm volatile("s_waitcnt vmcnt(" #N ")" ::: "memory")
#define SBAR() asm volatile("s_barrier" ::: "memory")

__device__ __forceinline__ int swz4(int row) {
  return (row & 3) ^ ((row >> 2) & 3);
}

__device__ __forceinline__ ushort f2bf(float f) {
  u32 u = __float_as_uint(f);
  return (ushort)((u + 0x7FFF + ((u >> 16) & 1)) >> 16);
}
__device__ __forceinline__ float bf2f(ushort u) {
  u32 v = ((u32)u) << 16;
  return __uint_as_float(v);
}

__device__ __forceinline__ void gload16(const void* g, void* l) {
  __builtin_amdgcn_global_load_lds(
      (const __attribute__((address_space(1))) u32*)g,
      (__attribute__((address_space(3))) u32*)l, 16, 0, 0);
}

// ---------------- fp32 VALU GEMM (static Wf GEMMs only), z=which -------------
#define BKK 32
#define LDSP 68
__global__ __launch_bounds__(256) void gemm_generic(
    const float* __restrict__ A, const float* __restrict__ Bm, const float* __restrict__ Bm2,
    float* __restrict__ C, float* __restrict__ C2,
    int M, int N, int K, long sAi, long sAk, long sBj, long sBk, long sCi)
{
  __shared__ __align__(16) float lds_a[BKK * LDSP];
  __shared__ __align__(16) float lds_b[BKK * LDSP];
  const float* Bb = blockIdx.z ? Bm2 : Bm;
  float* Cc = blockIdx.z ? C2 : C;
  const int i0 = blockIdx.y * 64;
  const int j0 = blockIdx.x * 64;
  const int tid = threadIdx.x;
  const int tx = tid & 15, ty = tid >> 4;
  float acc[4][4] = {};
  for (int k0 = 0; k0 < K; k0 += BKK) {
    for (int idx = tid; idx < BKK * 64; idx += 256) {
      int kk = idx & (BKK - 1), ii = idx >> 5;
      int gi = i0 + ii, gk = k0 + kk;
      lds_a[kk * LDSP + ii] = (gi < M && gk < K) ? A[(long)gi * sAi + (long)gk * sAk] : 0.f;
    }
    for (int idx = tid; idx < BKK * 64; idx += 256) {
      int kk = idx & (BKK - 1), jj = idx >> 5;
      int gj = j0 + jj, gk = k0 + kk;
      lds_b[kk * LDSP + jj] = (gj < N && gk < K) ? Bb[(long)gj * sBj + (long)gk * sBk] : 0.f;
    }
    __syncthreads();
    #pragma unroll
    for (int kk = 0; kk < BKK; ++kk) {
      const float4 a4 = *reinterpret_cast<const float4*>(&lds_a[kk * LDSP + ty * 4]);
      const float4 b4 = *reinterpret_cast<const float4*>(&lds_b[kk * LDSP + tx * 4]);
      const float av[4] = {a4.x, a4.y, a4.z, a4.w};
      const float bv[4] = {b4.x, b4.y, b4.z, b4.w};
      #pragma unroll
      for (int a = 0; a < 4; ++a)
        #pragma unroll
        for (int b = 0; b < 4; ++b)
          acc[a][b] = fmaf(av[a], bv[b], acc[a][b]);
    }
    __syncthreads();
  }
  for (int a = 0; a < 4; ++a) {
    int gi = i0 + ty * 4 + a;
    if (gi >= M) continue;
    for (int b = 0; b < 4; ++b) {
      int gj = j0 + tx * 4 + b;
      if (gj >= N) continue;
      Cc[(long)gi * sCi + gj] = acc[a][b];
    }
  }
}

// ---------------- merged k GEMM: 128x128 tile, bf16 out, z=which -------------
__global__ __launch_bounds__(256) void mfma_gemm(
    const ushort* __restrict__ A0, const ushort* __restrict__ A1,
    const ushort* __restrict__ B0, const ushort* __restrict__ B1,
    const float* __restrict__ bias0, const float* __restrict__ bias1,
    ushort* __restrict__ C0, ushort* __restrict__ C1,
    int M, int N, int K, long sAi, long sBj, long sCi)
{
  __shared__ ushort As[128 * 64];
  __shared__ ushort Bs[128 * 64];
  const int which = blockIdx.z;
  const ushort* Ab = which ? A1 : A0;
  const ushort* Bb = which ? B1 : B0;
  const float* bias = which ? bias1 : bias0;
  ushort* C = which ? C1 : C0;
  const int i0 = blockIdx.y * 128;
  const int j0 = blockIdx.x * 128;
  const int tid = threadIdx.x;
  const int wave = tid >> 6, lane = tid & 63;
  const int wm = wave >> 1, wn = wave & 1;
  const int col16 = lane & 15, krow = lane >> 4;

  f32x4 acc[4][4] = {};

  for (int k0 = 0; k0 < K; k0 += 64) {
    #pragma unroll
    for (int it = 0; it < 4; ++it) {
      int chunk = it * 256 + wave * 64 + lane;
      int row = chunk >> 3, s = chunk & 7;
      int kc = s ^ (row & 7);
      int gi = i0 + row; if (gi >= M) gi = M - 1;
      gload16(Ab + (long)gi * sAi + k0 + kc * 8, &As[chunk * 8]);
    }
    #pragma unroll
    for (int it = 0; it < 4; ++it) {
      int chunk = it * 256 + wave * 64 + lane;
      int row = chunk >> 3, s = chunk & 7;
      int kc = s ^ (row & 7);
      int gj = j0 + row; if (gj >= N) gj = N - 1;
      gload16(Bb + (long)gj * sBj + k0 + kc * 8, &Bs[chunk * 8]);
    }
    __syncthreads();
    #pragma unroll
    for (int ks = 0; ks < 2; ++ks) {
      short8 af[4], bfr[4];
      #pragma unroll
      for (int mi = 0; mi < 4; ++mi) {
        int row = wm * 64 + mi * 16 + col16;
        int slot = (ks * 4 + krow) ^ (row & 7);
        af[mi] = *(const short8*)&As[row * 64 + slot * 8];
      }
      #pragma unroll
      for (int nj = 0; nj < 4; ++nj) {
        int row = wn * 64 + nj * 16 + col16;
        int slot = (ks * 4 + krow) ^ (row & 7);
        bfr[nj] = *(const short8*)&Bs[row * 64 + slot * 8];
      }
      #pragma unroll
      for (int mi = 0; mi < 4; ++mi)
        #pragma unroll
        for (int nj = 0; nj < 4; ++nj)
          acc[mi][nj] = __builtin_amdgcn_mfma_f32_16x16x32_bf16(
              af[mi], bfr[nj], acc[mi][nj], 0, 0, 0);
    }
    __syncthreads();
  }

  const int r0 = krow * 4;
  #pragma unroll
  for (int mi = 0; mi < 4; ++mi) {
    int gi0 = i0 + wm * 64 + mi * 16 + r0;
    #pragma unroll
    for (int nj = 0; nj < 4; ++nj) {
      int gj = j0 + wn * 64 + nj * 16 + col16;
      f32x4 a = acc[mi][nj];
      #pragma unroll
      for (int r = 0; r < 4; ++r) {
        int gi = gi0 + r;
        if (gi >= M || gj >= N) continue;
        C[(long)gi * sCi + gj] = f2bf(a[r] + bias[gj]);
      }
    }
  }
}

// ---------------- transpose k (bf16): per batch [96][197]-view -> [197][128] -
__global__ __launch_bounds__(256) void transpose_k(
    const ushort* __restrict__ k1, const ushort* __restrict__ k2,
    ushort* __restrict__ EA1, ushort* __restrict__ EA2, int Bc)
{
  __shared__ ushort tile[32][33];
  int z = blockIdx.z;
  int which = (z >= Bc) ? 1 : 0;
  int b = which ? z - Bc : z;
  const ushort* src = (which ? k2 : k1) + (long)b * 18912;
  ushort* dst = (which ? EA2 : EA1) + (long)b * 25216;
  int l0 = blockIdx.x * 32, c0 = blockIdx.y * 32;
  int tx = threadIdx.x & 31, ty = threadIdx.x >> 5;
  for (int r = ty; r < 32; r += 8) {
    int c = c0 + r, l = l0 + tx;
    tile[r][tx] = (c < 96 && l < 197) ? src[(long)c * 197 + l] : (ushort)0;
  }
  __syncthreads();
  for (int r = ty; r < 32; r += 8) {
    int l = l0 + r, c = c0 + tx;
    if (l < 197 && c < 128) dst[(long)l * 128 + c] = tile[tx][r];
  }
}

// ---------------- energy GEMM (MFMA): E = EA1 . EA2^T, dual bf16 write -------
__global__ __launch_bounds__(256) void energy_mfma(
    const ushort* __restrict__ EA1, const ushort* __restrict__ EA2,
    ushort* __restrict__ Eb, ushort* __restrict__ ETb)
{
  __shared__ ushort elds[16896];     // staging 2x8192; bounce [128][132]
  ushort* As = elds;
  ushort* Bs = elds + 8192;
  const int bz = blockIdx.z;
  const ushort* Ab = EA1 + 25216L * bz;
  const ushort* Bb = EA2 + 25216L * bz;
  const int i0 = blockIdx.y * 128;   // l
  const int j0 = blockIdx.x * 128;   // m
  const int tid = threadIdx.x;
  const int wave = tid >> 6, lane = tid & 63;
  const int wm = wave >> 1, wn = wave & 1;
  const int col16 = lane & 15, krow = lane >> 4;

  f32x4 acc[4][4] = {};

  for (int k0 = 0; k0 < 128; k0 += 64) {
    #pragma unroll
    for (int it = 0; it < 4; ++it) {
      int chunk = it * 256 + wave * 64 + lane;
      int row = chunk >> 3, s = chunk & 7;
      int kc = s ^ (row & 7);
      int gi = i0 + row; if (gi > 196) gi = 196;
      gload16(Ab + (long)gi * 128 + k0 + kc * 8, &As[chunk * 8]);
    }
    #pragma unroll
    for (int it = 0; it < 4; ++it) {
      int chunk = it * 256 + wave * 64 + lane;
      int row = chunk >> 3, s = chunk & 7;
      int kc = s ^ (row & 7);
      int gj = j0 + row; if (gj > 196) gj = 196;
      gload16(Bb + (long)gj * 128 + k0 + kc * 8, &Bs[chunk * 8]);
    }
    __syncthreads();
    #pragma unroll
    for (int ks = 0; ks < 2; ++ks) {
      short8 af[4], bfr[4];
      #pragma unroll
      for (int mi = 0; mi < 4; ++mi) {
        int row = wm * 64 + mi * 16 + col16;
        int slot = (ks * 4 + krow) ^ (row & 7);
        af[mi] = *(const short8*)&As[row * 64 + slot * 8];
      }
      #pragma unroll
      for (int nj = 0; nj < 4; ++nj) {
        int row = wn * 64 + nj * 16 + col16;
        int slot = (ks * 4 + krow) ^ (row & 7);
        bfr[nj] = *(const short8*)&Bs[row * 64 + slot * 8];
      }
      #pragma unroll
      for (int mi = 0; mi < 4; ++mi)
        #pragma unroll
        for (int nj = 0; nj < 4; ++nj)
          acc[mi][nj] = __builtin_amdgcn_mfma_f32_16x16x32_bf16(
              af[mi], bfr[nj], acc[mi][nj], 0, 0, 0);
    }
    __syncthreads();
  }

  ushort* obufT = elds;
  #pragma unroll
  for (int mi = 0; mi < 4; ++mi)
    #pragma unroll
    for (int nj = 0; nj < 4; ++nj) {
      int mcol = wn * 64 + nj * 16 + col16;
      int lrow = wm * 64 + mi * 16 + krow * 4;
      bfx4 h;
      #pragma unroll
      for (int r = 0; r < 4; ++r) h[r] = f2bf(acc[mi][nj][r]);
      *(bfx4*)&obufT[mcol * 132 + lrow] = h;
    }
  SBAR();
  {
    int lL = tid & 63, mg = tid >> 6;
    for (int it = 0; it < 32; ++it) {
      int mL = mg * 32 + it;
      int gm = j0 + mL;
      if (gm >= 197) break;
      #pragma unroll
      for (int lh = 0; lh < 2; ++lh) {
        int l = lh * 64 + lL;
        int gl = i0 + l;
        if (gl < 224)
          ETb[bz * 50432L + (long)gm * 256 + gl] =
              (gl < 197) ? obufT[mL * 132 + l] : (ushort)0;
      }
    }
  }
  {
    int mL = tid & 63, lg = tid >> 6;
    for (int it = 0; it < 32; ++it) {
      int lL = lg * 32 + it;
      int gl = i0 + lL;
      if (gl >= 197) break;
      #pragma unroll
      for (int mh = 0; mh < 2; ++mh) {
        int m = mh * 64 + mL;
        int gm = j0 + m;
        if (gm < 224)
          Eb[bz * 50432L + (long)gl * 256 + gm] =
              (gm < 197) ? obufT[m * 132 + lL] : (ushort)0;
      }
    }
  }
}

// ---------------- flat v GEMM: 256 threads, 128x128 tile, 64x64 wave tiles ---
__global__ __launch_bounds__(256) void vbig_gemm(
    const ushort* __restrict__ A0, const ushort* __restrict__ A1,
    const ushort* __restrict__ B0, const ushort* __restrict__ B1,
    const float* __restrict__ bias0, const float* __restrict__ bias1,
    ushort* __restrict__ C0, ushort* __restrict__ C1,
    int ntiles, long Nc)
{
  __shared__ ushort As[2][128 * 32];   // 8 KB each
  __shared__ ushort Bs[2][128 * 32];
  const int per = 6 * ntiles;
  int bid = blockIdx.x;
  const int which = bid / per;
  bid -= which * per;
  int mtile, ntile;
  if ((ntiles & 7) == 0) {
    int xcd = bid & 7;
    int grp = bid >> 3;
    mtile = grp % 6;
    ntile = (grp / 6) * 8 + xcd;       // same-(sblk,xcd) blocks share B panel
  } else {
    ntile = bid % ntiles;
    mtile = bid / ntiles;
  }
  const ushort* Ab = (which ? A1 : A0) + (long)(mtile * 128) * 768;
  const ushort* Bb = which ? B1 : B0;
  const float* bias = which ? bias1 : bias0;
  ushort* C = which ? C1 : C0;
  const int n0 = ntile * 128;
  const int tid = threadIdx.x, wave = tid >> 6, lane = tid & 63;
  const int wm = wave >> 1, wn = wave & 1;   // 2x2 wave grid: 64 x 64 tiles
  const int col16 = lane & 15, kq = lane >> 4;

  f32x4 acc[4][4] = {};

  // 16 chunks of 1 KB; wave w stages {4w..4w+3}.
  auto stage = [&](int buf, int k0) {
    const int lrow = lane >> 2, s = lane & 3;
    #pragma unroll
    for (int c0 = 0; c0 < 4; ++c0) {
      int c = wave * 4 + c0;
      if (c < 8) {
        int row = c * 16 + lrow;
        int kc = s ^ swz4(row);
        gload16(Ab + (long)row * 768 + k0 + kc * 8,
                (char*)(&As[buf][0]) + c * 1024 + lane * 16);
      } else {
        int j = (c - 8) * 16 + lrow;
        int n = n0 + j;
        int b = n / 224;
        int l = n - b * 224;
        int grow = b * 197 + (l < 197 ? l : 196);
        int kc = s ^ swz4(j);
        gload16(Bb + (long)grow * 768 + k0 + kc * 8,
                (char*)(&Bs[buf][0]) + (c - 8) * 1024 + lane * 16);
      }
    }
  };

  stage(0, 0);
  for (int t = 0; t < 24; ++t) {
    int cur = t & 1;
    if (t + 1 < 24) {
      stage(cur ^ 1, (t + 1) << 5);
      VM_WAIT(4);                 // own 4 next-stage loads in flight
    } else {
      VM_WAIT(0);
    }
    SBAR();
    short8 af[4], bfr[4];
    #pragma unroll
    for (int mi = 0; mi < 4; ++mi) {
      int arow = wm * 64 + mi * 16 + col16;
      af[mi] = *(const short8*)((const char*)(&As[cur][0]) +
                                arow * 64 + ((kq ^ swz4(arow)) << 4));
    }
    #pragma unroll
    for (int nj = 0; nj < 4; ++nj) {
      int brow = wn * 64 + nj * 16 + col16;
      bfr[nj] = *(const short8*)((const char*)(&Bs[cur][0]) +
                                 brow * 64 + ((kq ^ swz4(brow)) << 4));
    }
    #pragma unroll
    for (int mi = 0; mi < 4; ++mi)
      #pragma unroll
      for (int nj = 0; nj < 4; ++nj)
        acc[mi][nj] = __builtin_amdgcn_mfma_f32_16x16x32_bf16(
            af[mi], bfr[nj], acc[mi][nj], 0, 0, 0);
    SBAR();
  }

  #pragma unroll
  for (int mi = 0; mi < 4; ++mi) {
    #pragma unroll
    for (int r = 0; r < 4; ++r) {
      int gi = mtile * 128 + wm * 64 + mi * 16 + kq * 4 + r;
      float bv = bias[gi];
      long base = (long)gi * Nc;
      #pragma unroll
      for (int nj = 0; nj < 4; ++nj) {
        int n = n0 + wn * 64 + nj * 16 + col16;
        int b = n / 224;
        int l = n - b * 224;
        C[base + n] = (l < 197) ? f2bf(acc[mi][nj][r] + bv) : (ushort)0;
      }
    }
  }
}

// ---------------- fused att-logit GEMM + column softmax, counted vmcnt -------
__global__ __launch_bounds__(256) void att_gemm(
    const ushort* __restrict__ Wl0, const ushort* __restrict__ Wl1,
    const ushort* __restrict__ E0, const ushort* __restrict__ E1,
    const float* __restrict__ bl0, const float* __restrict__ bl1,
    ushort* __restrict__ a0, ushort* __restrict__ a1out)
{
  __shared__ ushort Aws[2][208 * 32];
  __shared__ ushort Bws[2][64 * 32];
  __shared__ float blds[208];
  const int which = blockIdx.z;
  const int bz = blockIdx.y;
  const ushort* Wl = which ? Wl1 : Wl0;
  const ushort* Bb = (which ? E1 : E0) + 50432L * bz;
  const float* bl = which ? bl1 : bl0;
  ushort* aout = which ? a1out : a0;
  const int l0 = blockIdx.x * 64;
  const int tid = threadIdx.x, wave = tid >> 6, lane = tid & 63;
  const int col16 = lane & 15, kq = lane >> 4;

  if (tid < 208) blds[tid] = (tid < 197) ? bl[tid] : 0.f;

  f32x4 acc[13] = {};

  auto stage = [&](int buf, int k0) {
    const int lrow = lane >> 2, s = lane & 3;
    #pragma unroll
    for (int c0 = 0; c0 < 5; ++c0) {
      int c = wave + c0 * 4;
      if (c >= 17) break;
      if (c < 13) {
        int row = c * 16 + lrow;
        int gr = row < 197 ? row : 196;
        int kc = s ^ swz4(row);
        gload16(Wl + (long)gr * 256 + k0 + kc * 8,
                (char*)(&Aws[buf][0]) + c * 1024 + lane * 16);
      } else {
        int row = (c - 13) * 16 + lrow;
        int gl = l0 + row; if (gl > 196) gl = 196;
        int kc = s ^ swz4(row);
        gload16(Bb + (long)gl * 256 + k0 + kc * 8,
                (char*)(&Bws[buf][0]) + (c - 13) * 1024 + lane * 16);
      }
    }
  };

  stage(0, 0);
  for (int t = 0; t < 7; ++t) {
    int cur = t & 1;
    if (t + 1 < 7) {
      stage(cur ^ 1, (t + 1) * 32);
      if (wave == 0) VM_WAIT(5); else VM_WAIT(4);
    } else {
      VM_WAIT(0);
    }
    SBAR();
    int brow = wave * 16 + col16;
    short8 bf = *(const short8*)((const char*)(&Bws[cur][0]) +
                                 brow * 64 + ((kq ^ swz4(brow)) << 4));
    #pragma unroll
    for (int j = 0; j < 13; ++j) {
      int arow = j * 16 + col16;
      short8 af = *(const short8*)((const char*)(&Aws[cur][0]) +
                                   arow * 64 + ((kq ^ swz4(arow)) << 4));
      acc[j] = __builtin_amdgcn_mfma_f32_16x16x32_bf16(af, bf, acc[j], 0, 0, 0);
    }
    SBAR();
  }

  const int c = l0 + wave * 16 + col16;
  float mx = -INFINITY;
  #pragma unroll
  for (int j = 0; j < 13; ++j)
    #pragma unroll
    for (int r = 0; r < 4; ++r) {
      int m = j * 16 + kq * 4 + r;
      float v = acc[j][r] + blds[m];
      v = (m < 197) ? v : -INFINITY;
      acc[j][r] = v;
      mx = fmaxf(mx, v);
    }
  mx = fmaxf(mx, __shfl_xor(mx, 16));
  mx = fmaxf(mx, __shfl_xor(mx, 32));
  float s = 0.f;
  #pragma unroll
  for (int j = 0; j < 13; ++j)
    #pragma unroll
    for (int r = 0; r < 4; ++r) {
      int m = j * 16 + kq * 4 + r;
      float e = (m < 197) ? __expf(acc[j][r] - mx) : 0.f;
      acc[j][r] = e;
      s += e;
    }
  s += __shfl_xor(s, 16);
  s += __shfl_xor(s, 32);
  const float inv = 1.f / s;
  ushort* ab = aout + 50432L * bz;
  #pragma unroll
  for (int j = 0; j < 13; ++j)
    #pragma unroll
    for (int r = 0; r < 4; ++r) {
      int m = j * 16 + kq * 4 + r;
      if (m < 197)
        ab[(long)m * 256 + c] = (c < 197) ? f2bf(acc[j][r] * inv) : (ushort)0;
    }
}

// ---------------- out GEMM: 512 threads, 128x224 tile, bounce-v2 drain -------
__global__ __launch_bounds__(512) void vout_gemm(
    const ushort* __restrict__ A0, const ushort* __restrict__ A1,
    const ushort* __restrict__ B0, const ushort* __restrict__ B1,
    const ushort* __restrict__ resid0, const ushort* __restrict__ resid1,
    const float* __restrict__ g0, const float* __restrict__ g1,
    float* __restrict__ C0, float* __restrict__ C1,
    int N, int K, long sAi, long bAs, long sBj, long bBs,
    long sCi, long bCs, int mtiles, int batches)
{
  __shared__ ushort lds_all[22528];       // A dbuf 2x4096 | B dbuf 2x7168
  const int per = mtiles * batches;
  int bid = blockIdx.x;
  const int which = bid / per;
  bid -= which * per;
  const ushort* A = which ? A1 : A0;
  const ushort* Bm = which ? B1 : B0;
  const ushort* resid = which ? resid1 : resid0;
  const float* gammaPtr = which ? g1 : g0;
  float* C = which ? C1 : C0;

  int mtile, bz;
  if ((batches & 7) == 0) {
    int xcd = bid & 7, sid = bid >> 3;
    mtile = sid % mtiles;
    bz = (sid / mtiles) * 8 + xcd;
  } else {
    mtile = bid % mtiles;
    bz = bid / mtiles;
  }
  const ushort* Ab = A + bAs * bz + (long)(mtile * 128) * sAi;
  const ushort* Bb = Bm + bBs * bz;
  const int tid = threadIdx.x, wave = tid >> 6, lane = tid & 63;
  const int wr = wave >> 1, wc = wave & 1;    // 4x2 grid: 32 x 112 tiles
  const int col16 = lane & 15, kq = lane >> 4;

  f32x4 acc[2][7] = {};

  auto stage = [&](int buf, int k0) {
    const int lrow = lane >> 2, s = lane & 3;
    #pragma unroll
    for (int c0 = 0; c0 < 3; ++c0) {
      int c = wave + c0 * 8;
      if (c >= 22) break;
      if (c < 8) {
        int row = c * 16 + lrow;
        int kc = s ^ swz4(row);
        gload16(Ab + (long)row * sAi + k0 + kc * 8,
                (char*)lds_all + buf * 8192 + c * 1024 + lane * 16);
      } else {
        int row = (c - 8) * 16 + lrow;
        int gj = row < N ? row : N - 1;
        int kc = s ^ swz4(row);
        gload16(Bb + (long)gj * sBj + k0 + kc * 8,
                (char*)lds_all + 16384 + buf * 14336 + (c - 8) * 1024 + lane * 16);
      }
    }
  };

  const int nt = K >> 5;
  stage(0, 0);
  for (int t = 0; t < nt; ++t) {
    int cur = t & 1;
    if (t + 1 < nt) {
      stage(cur ^ 1, (t + 1) << 5);
      if (wave < 6) VM_WAIT(3); else VM_WAIT(2);
    } else {
      VM_WAIT(0);
    }
    SBAR();
    short8 af[2];
    #pragma unroll
    for (int mi = 0; mi < 2; ++mi) {
      int arow = wr * 32 + mi * 16 + col16;
      af[mi] = *(const short8*)((const char*)lds_all + cur * 8192 +
                                arow * 64 + ((kq ^ swz4(arow)) << 4));
    }
    #pragma unroll
    for (int nj = 0; nj < 7; ++nj) {
      int brow = wc * 112 + nj * 16 + col16;
      short8 bf = *(const short8*)((const char*)lds_all + 16384 + cur * 14336 +
                                   brow * 64 + ((kq ^ swz4(brow)) << 4));
      #pragma unroll
      for (int mi = 0; mi < 2; ++mi)
        acc[mi][nj] = __builtin_amdgcn_mfma_f32_16x16x32_bf16(
            af[mi], bf, acc[mi][nj], 0, 0, 0);
    }
    SBAR();
  }

  // bounce-v2: obufT [112 cols][132 rows] bf16, parallel dump per col-chunk.
  const float g = gammaPtr[0];
  ushort* obufT = lds_all;
  #pragma unroll 1
  for (int c = 0; c < 2; ++c) {
    if (wc == c) {
      #pragma unroll
      for (int mi = 0; mi < 2; ++mi)
        #pragma unroll
        for (int nj = 0; nj < 7; ++nj) {
          int colL = nj * 16 + col16;
          int row = wr * 32 + mi * 16 + kq * 4;
          bfx4 h;
          #pragma unroll
          for (int r = 0; r < 4; ++r) h[r] = f2bf(g * acc[mi][nj][r]);
          *(bfx4*)&obufT[colL * 132 + row] = h;
        }
    }
    SBAR();
    {
      int colL = tid & 127, rg = tid >> 7;
      int ncols = 197 - c * 112; if (ncols > 112) ncols = 112;
      if (colL < ncols) {
        int gcol = c * 112 + colL;
        #pragma unroll 4
        for (int it = 0; it < 32; ++it) {
          int row = rg * 32 + it;
          long ci = bCs * bz + (long)(mtile * 128 + row) * 197 + gcol;
          C[ci] = bf2f(obufT[colL * 132 + row]) + bf2f(resid[ci]);
        }
      }
    }
    SBAR();
  }
}

// ---------------- merged small helpers ---------------------------------------
__global__ void fuse_bias2(const float* __restrict__ Wks,
                           const float* __restrict__ bk1, const float* __restrict__ bk2,
                           const float* __restrict__ bks,
                           float* __restrict__ bf1, float* __restrict__ bf2) {
  int c = threadIdx.x;
  if (c >= 192) return;
  const float* bk = (c < 96) ? bk1 : bk2;
  float* bf = (c < 96) ? bf1 : bf2;
  int cc = (c < 96) ? c : c - 96;
  float s = bks[cc];
  for (int e = 0; e < 96; ++e) s += Wks[cc * 96 + e] * bk[e];
  bf[cc] = s;
}

__global__ __launch_bounds__(256) void conv_weights(
    const float* __restrict__ Wf1, const float* __restrict__ Wf2,
    const float* __restrict__ Wv1, const float* __restrict__ Wv2,
    const float* __restrict__ Wl1, const float* __restrict__ Wl2,
    ushort* __restrict__ Wf1b, ushort* __restrict__ Wf2b,
    ushort* __restrict__ Wv1b, ushort* __restrict__ Wv2b,
    ushort* __restrict__ Wl1b, ushort* __restrict__ Wl2b)
{
  const long total = 147456 + 1179648 + 100864;
  long stride = (long)gridDim.x * blockDim.x;
  for (long i = (long)blockIdx.x * blockDim.x + threadIdx.x; i < total; i += stride) {
    if (i < 147456) {
      long j = i;
      if (j < 73728) Wf1b[j] = f2bf(Wf1[j]);
      else Wf2b[j - 73728] = f2bf(Wf2[j - 73728]);
    } else if (i < 147456 + 1179648) {
      long j = i - 147456;
      if (j < 589824) Wv1b[j] = f2bf(Wv1[j]);
      else Wv2b[j - 589824] = f2bf(Wv2[j - 589824]);
    } else {
      long j = i - 147456 - 1179648;
      int w2 = j >= 50432;
      if (w2) j -= 50432;
      int r = (int)(j >> 8), cc = (int)(j & 255);
      const float* s = w2 ? Wl2 : Wl1;
      ushort* d = w2 ? Wl2b : Wl1b;
      d[j] = (cc < 197) ? f2bf(s[(long)r * 197 + cc]) : (ushort)0;
    }
  }
}

__global__ __launch_bounds__(256) void conv_xy(const float* __restrict__ x,
                                               const float* __restrict__ y,
                                               ushort* __restrict__ xb,
                                               ushort* __restrict__ yb, long n8) {
  long i = (long)blockIdx.x * blockDim.x + threadIdx.x;
  long stride = (long)gridDim.x * blockDim.x;
  for (; i < 2 * n8; i += stride) {
    const float* s = (i < n8) ? x : y;
    ushort* d = (i < n8) ? xb : yb;
    long j = (i < n8) ? i : i - n8;
    float4 a = ((const float4*)s)[2 * j];
    float4 b = ((const float4*)s)[2 * j + 1];
    ushort8 o;
    o[0] = f2bf(a.x); o[1] = f2bf(a.y); o[2] = f2bf(a.z); o[3] = f2bf(a.w);
    o[4] = f2bf(b.x); o[5] = f2bf(b.y); o[6] = f2bf(b.z); o[7] = f2bf(b.w);
    *(ushort8*)&d[j * 8] = o;
  }
}

// ---------------- launcher ---------------------------------------------------
extern "C" void kernel_launch(void* const* d_in, const int* in_sizes, int n_in,
                              void* d_out, int out_size, void* d_ws, size_t ws_size,
                              hipStream_t stream) {
  const float* x   = (const float*)d_in[0];
  const float* y   = (const float*)d_in[1];
  const float* Wk1 = (const float*)d_in[2];
  const float* bk1 = (const float*)d_in[3];
  const float* Wk2 = (const float*)d_in[4];
  const float* bk2 = (const float*)d_in[5];
  const float* Wks = (const float*)d_in[6];
  const float* bks = (const float*)d_in[7];
  const float* Wl1 = (const float*)d_in[8];
  const float* bl1 = (const float*)d_in[9];
  const float* Wl2 = (const float*)d_in[10];
  const float* bl2 = (const float*)d_in[11];
  const float* Wv1 = (const float*)d_in[12];
  const float* bv1 = (const float*)d_in[13];
  const float* Wv2 = (const float*)d_in[14];
  const float* bv2 = (const float*)d_in[15];
  const float* gamma1 = (const float*)d_in[16];
  const float* gamma2 = (const float*)d_in[17];
  float* out = (float*)d_out;

  const int B = 256, L = 197, D = 768;
  const long LD = (long)L * D;     // 151296

  const size_t staticBytes = 3446784;
  const size_t perB = 605184 + 75648 + 100864 + 201728 + 201728 + 688128;
  int Bc = 256;
  while (Bc > 8 && staticBytes + (size_t)Bc * perB > ws_size) Bc >>= 1;

  char* p = (char*)d_ws;
  auto carve = [&](size_t bytes) { char* r = p; p += bytes; return r; };
  float*  Wf1   = (float*)carve(73728 * 4);
  float*  Wf2   = (float*)carve(73728 * 4);
  float*  bf1   = (float*)carve(512);
  float*  bf2   = (float*)carve(512);
  ushort* Wv1b  = (ushort*)carve(589824 * 2);
  ushort* Wv2b  = (ushort*)carve(589824 * 2);
  ushort* Wf1b  = (ushort*)carve(73728 * 2);
  ushort* Wf2b  = (ushort*)carve(73728 * 2);
  ushort* Wl1b  = (ushort*)carve(50432 * 2);
  ushort* Wl2b  = (ushort*)carve(50432 * 2);
  ushort* xb    = (ushort*)carve((size_t)Bc * LD * 2);
  ushort* yb    = (ushort*)carve((size_t)Bc * LD * 2);
  ushort* k1    = (ushort*)carve((size_t)Bc * 18912 * 2);
  ushort* k2    = (ushort*)carve((size_t)Bc * 18912 * 2);
  ushort* EA1   = (ushort*)carve((size_t)Bc * 25216 * 2);
  ushort* EA2   = (ushort*)carve((size_t)Bc * 25216 * 2);
  ushort* Eb    = (ushort*)carve((size_t)Bc * 50432 * 2);
  ushort* ETbuf = (ushort*)carve((size_t)Bc * 50432 * 2);
  ushort* a1    = (ushort*)carve((size_t)Bc * 50432 * 2);
  ushort* a2    = (ushort*)carve((size_t)Bc * 50432 * 2);
  const long Nc = (long)Bc * 224;
  ushort* vT    = (ushort*)carve((size_t)768 * Nc * 2);
  ushort* vT2   = (ushort*)carve((size_t)768 * Nc * 2);

  dim3 blk(256);

  gemm_generic<<<dim3(12, 2, 2), blk, 0, stream>>>(Wks, Wk1, Wk2, Wf1, Wf2,
      96, 768, 96, 96, 1, 1, 768, 768);
  fuse_bias2<<<1, 192, 0, stream>>>(Wks, bk1, bk2, bks, bf1, bf2);
  conv_weights<<<dim3(1024), blk, 0, stream>>>(Wf1, Wf2, Wv1, Wv2, Wl1, Wl2,
      Wf1b, Wf2b, Wv1b, Wv2b, Wl1b, Wl2b);

  for (int c0 = 0; c0 < B; c0 += Bc) {
    const float* xc = x + (long)c0 * LD;
    const float* yc = y + (long)c0 * LD;
    const int Mr = Bc * L;
    const int gym = (Mr + 127) / 128;

    conv_xy<<<dim3(2048), blk, 0, stream>>>(xc, yc, xb, yb, (long)Bc * LD / 8);

    mfma_gemm<<<dim3(1, gym, 2), blk, 0, stream>>>(xb, yb, Wf1b, Wf2b, bf1, bf2,
        k1, k2, Mr, 96, 768, 768, 768, 96);

    transpose_k<<<dim3(7, 4, 2 * Bc), blk, 0, stream>>>(k1, k2, EA1, EA2, Bc);

    energy_mfma<<<dim3(2, 2, Bc), blk, 0, stream>>>(EA1, EA2, Eb, ETbuf);

    att_gemm<<<dim3(4, Bc, 2), blk, 0, stream>>>(Wl1b, Wl2b, Eb, ETbuf,
        bl1, bl2, a1, a2);

    {
      int ntiles = (int)(Nc / 128);
      vbig_gemm<<<dim3(2 * 6 * ntiles), blk, 0, stream>>>(
          Wv2b, Wv1b, yb, xb, bv2, bv1, vT, vT2, ntiles, Nc);
    }

    vout_gemm<<<dim3(12 * Bc), dim3(512), 0, stream>>>(vT, vT2, a1, a2,
        xb, yb, gamma1, gamma2,
        out + (long)c0 * LD, out + (long)B * LD + (long)c0 * LD,
        197, 224, Nc, 224, 256, 50432, 197, LD, 6, Bc);
  }
}

// Round 17
// 636.725 us; speedup vs baseline: 1.0927x; 1.0403x over previous
//
#include <hip/hip_runtime.h>
#include <math.h>

typedef unsigned short ushort;
typedef __attribute__((ext_vector_type(4))) unsigned short bfx4;
typedef __attribute__((ext_vector_type(8))) short short8;
typedef __attribute__((ext_vector_type(8))) unsigned short ushort8;
typedef __attribute__((ext_vector_type(4))) float f32x4;
typedef unsigned int u32;

#define VM_WAIT(N) asm volatile("s_waitcnt vmcnt(" #N ")" ::: "memory")
#define LGKM_WAIT() asm volatile("s_waitcnt lgkmcnt(0)" ::: "memory")
#define SBAR() asm volatile("s_barrier" ::: "memory")

__device__ __forceinline__ int swz4(int row) {
  return (row & 3) ^ ((row >> 2) & 3);
}

__device__ __forceinline__ ushort f2bf(float f) {
  u32 u = __float_as_uint(f);
  return (ushort)((u + 0x7FFF + ((u >> 16) & 1)) >> 16);
}
__device__ __forceinline__ float bf2f(ushort u) {
  u32 v = ((u32)u) << 16;
  return __uint_as_float(v);
}

__device__ __forceinline__ void gload16(const void* g, void* l) {
  __builtin_amdgcn_global_load_lds(
      (const __attribute__((address_space(1))) u32*)g,
      (__attribute__((address_space(3))) u32*)l, 16, 0, 0);
}

// ---------------- fp32 VALU GEMM (static Wf GEMMs only), z=which -------------
#define BKK 32
#define LDSP 68
__global__ __launch_bounds__(256) void gemm_generic(
    const float* __restrict__ A, const float* __restrict__ Bm, const float* __restrict__ Bm2,
    float* __restrict__ C, float* __restrict__ C2,
    int M, int N, int K, long sAi, long sAk, long sBj, long sBk, long sCi)
{
  __shared__ __align__(16) float lds_a[BKK * LDSP];
  __shared__ __align__(16) float lds_b[BKK * LDSP];
  const float* Bb = blockIdx.z ? Bm2 : Bm;
  float* Cc = blockIdx.z ? C2 : C;
  const int i0 = blockIdx.y * 64;
  const int j0 = blockIdx.x * 64;
  const int tid = threadIdx.x;
  const int tx = tid & 15, ty = tid >> 4;
  float acc[4][4] = {};
  for (int k0 = 0; k0 < K; k0 += BKK) {
    for (int idx = tid; idx < BKK * 64; idx += 256) {
      int kk = idx & (BKK - 1), ii = idx >> 5;
      int gi = i0 + ii, gk = k0 + kk;
      lds_a[kk * LDSP + ii] = (gi < M && gk < K) ? A[(long)gi * sAi + (long)gk * sAk] : 0.f;
    }
    for (int idx = tid; idx < BKK * 64; idx += 256) {
      int kk = idx & (BKK - 1), jj = idx >> 5;
      int gj = j0 + jj, gk = k0 + kk;
      lds_b[kk * LDSP + jj] = (gj < N && gk < K) ? Bb[(long)gj * sBj + (long)gk * sBk] : 0.f;
    }
    __syncthreads();
    #pragma unroll
    for (int kk = 0; kk < BKK; ++kk) {
      const float4 a4 = *reinterpret_cast<const float4*>(&lds_a[kk * LDSP + ty * 4]);
      const float4 b4 = *reinterpret_cast<const float4*>(&lds_b[kk * LDSP + tx * 4]);
      const float av[4] = {a4.x, a4.y, a4.z, a4.w};
      const float bv[4] = {b4.x, b4.y, b4.z, b4.w};
      #pragma unroll
      for (int a = 0; a < 4; ++a)
        #pragma unroll
        for (int b = 0; b < 4; ++b)
          acc[a][b] = fmaf(av[a], bv[b], acc[a][b]);
    }
    __syncthreads();
  }
  for (int a = 0; a < 4; ++a) {
    int gi = i0 + ty * 4 + a;
    if (gi >= M) continue;
    for (int b = 0; b < 4; ++b) {
      int gj = j0 + tx * 4 + b;
      if (gj >= N) continue;
      Cc[(long)gi * sCi + gj] = acc[a][b];
    }
  }
}

// ---------------- merged k GEMM: 128x128 tile, bf16 out, z=which -------------
__global__ __launch_bounds__(256) void mfma_gemm(
    const ushort* __restrict__ A0, const ushort* __restrict__ A1,
    const ushort* __restrict__ B0, const ushort* __restrict__ B1,
    const float* __restrict__ bias0, const float* __restrict__ bias1,
    ushort* __restrict__ C0, ushort* __restrict__ C1,
    int M, int N, int K, long sAi, long sBj, long sCi)
{
  __shared__ ushort As[128 * 64];
  __shared__ ushort Bs[128 * 64];
  const int which = blockIdx.z;
  const ushort* Ab = which ? A1 : A0;
  const ushort* Bb = which ? B1 : B0;
  const float* bias = which ? bias1 : bias0;
  ushort* C = which ? C1 : C0;
  const int i0 = blockIdx.y * 128;
  const int j0 = blockIdx.x * 128;
  const int tid = threadIdx.x;
  const int wave = tid >> 6, lane = tid & 63;
  const int wm = wave >> 1, wn = wave & 1;
  const int col16 = lane & 15, krow = lane >> 4;

  f32x4 acc[4][4] = {};

  for (int k0 = 0; k0 < K; k0 += 64) {
    #pragma unroll
    for (int it = 0; it < 4; ++it) {
      int chunk = it * 256 + wave * 64 + lane;
      int row = chunk >> 3, s = chunk & 7;
      int kc = s ^ (row & 7);
      int gi = i0 + row; if (gi >= M) gi = M - 1;
      gload16(Ab + (long)gi * sAi + k0 + kc * 8, &As[chunk * 8]);
    }
    #pragma unroll
    for (int it = 0; it < 4; ++it) {
      int chunk = it * 256 + wave * 64 + lane;
      int row = chunk >> 3, s = chunk & 7;
      int kc = s ^ (row & 7);
      int gj = j0 + row; if (gj >= N) gj = N - 1;
      gload16(Bb + (long)gj * sBj + k0 + kc * 8, &Bs[chunk * 8]);
    }
    __syncthreads();
    #pragma unroll
    for (int ks = 0; ks < 2; ++ks) {
      short8 af[4], bfr[4];
      #pragma unroll
      for (int mi = 0; mi < 4; ++mi) {
        int row = wm * 64 + mi * 16 + col16;
        int slot = (ks * 4 + krow) ^ (row & 7);
        af[mi] = *(const short8*)&As[row * 64 + slot * 8];
      }
      #pragma unroll
      for (int nj = 0; nj < 4; ++nj) {
        int row = wn * 64 + nj * 16 + col16;
        int slot = (ks * 4 + krow) ^ (row & 7);
        bfr[nj] = *(const short8*)&Bs[row * 64 + slot * 8];
      }
      #pragma unroll
      for (int mi = 0; mi < 4; ++mi)
        #pragma unroll
        for (int nj = 0; nj < 4; ++nj)
          acc[mi][nj] = __builtin_amdgcn_mfma_f32_16x16x32_bf16(
              af[mi], bfr[nj], acc[mi][nj], 0, 0, 0);
    }
    __syncthreads();
  }

  const int r0 = krow * 4;
  #pragma unroll
  for (int mi = 0; mi < 4; ++mi) {
    int gi0 = i0 + wm * 64 + mi * 16 + r0;
    #pragma unroll
    for (int nj = 0; nj < 4; ++nj) {
      int gj = j0 + wn * 64 + nj * 16 + col16;
      f32x4 a = acc[mi][nj];
      #pragma unroll
      for (int r = 0; r < 4; ++r) {
        int gi = gi0 + r;
        if (gi >= M || gj >= N) continue;
        C[(long)gi * sCi + gj] = f2bf(a[r] + bias[gj]);
      }
    }
  }
}

// ---------------- transpose k (bf16): per batch [96][197]-view -> [197][128] -
__global__ __launch_bounds__(256) void transpose_k(
    const ushort* __restrict__ k1, const ushort* __restrict__ k2,
    ushort* __restrict__ EA1, ushort* __restrict__ EA2, int Bc)
{
  __shared__ ushort tile[32][33];
  int z = blockIdx.z;
  int which = (z >= Bc) ? 1 : 0;
  int b = which ? z - Bc : z;
  const ushort* src = (which ? k2 : k1) + (long)b * 18912;
  ushort* dst = (which ? EA2 : EA1) + (long)b * 25216;
  int l0 = blockIdx.x * 32, c0 = blockIdx.y * 32;
  int tx = threadIdx.x & 31, ty = threadIdx.x >> 5;
  for (int r = ty; r < 32; r += 8) {
    int c = c0 + r, l = l0 + tx;
    tile[r][tx] = (c < 96 && l < 197) ? src[(long)c * 197 + l] : (ushort)0;
  }
  __syncthreads();
  for (int r = ty; r < 32; r += 8) {
    int l = l0 + r, c = c0 + tx;
    if (l < 197 && c < 128) dst[(long)l * 128 + c] = tile[tx][r];
  }
}

// ---------------- energy GEMM (MFMA): E = EA1 . EA2^T, dual bf16 write -------
__global__ __launch_bounds__(256) void energy_mfma(
    const ushort* __restrict__ EA1, const ushort* __restrict__ EA2,
    ushort* __restrict__ Eb, ushort* __restrict__ ETb)
{
  __shared__ ushort elds[16896];     // staging 2x8192; bounce [128][132]
  ushort* As = elds;
  ushort* Bs = elds + 8192;
  const int bz = blockIdx.z;
  const ushort* Ab = EA1 + 25216L * bz;
  const ushort* Bb = EA2 + 25216L * bz;
  const int i0 = blockIdx.y * 128;   // l
  const int j0 = blockIdx.x * 128;   // m
  const int tid = threadIdx.x;
  const int wave = tid >> 6, lane = tid & 63;
  const int wm = wave >> 1, wn = wave & 1;
  const int col16 = lane & 15, krow = lane >> 4;

  f32x4 acc[4][4] = {};

  for (int k0 = 0; k0 < 128; k0 += 64) {
    #pragma unroll
    for (int it = 0; it < 4; ++it) {
      int chunk = it * 256 + wave * 64 + lane;
      int row = chunk >> 3, s = chunk & 7;
      int kc = s ^ (row & 7);
      int gi = i0 + row; if (gi > 196) gi = 196;
      gload16(Ab + (long)gi * 128 + k0 + kc * 8, &As[chunk * 8]);
    }
    #pragma unroll
    for (int it = 0; it < 4; ++it) {
      int chunk = it * 256 + wave * 64 + lane;
      int row = chunk >> 3, s = chunk & 7;
      int kc = s ^ (row & 7);
      int gj = j0 + row; if (gj > 196) gj = 196;
      gload16(Bb + (long)gj * 128 + k0 + kc * 8, &Bs[chunk * 8]);
    }
    __syncthreads();
    #pragma unroll
    for (int ks = 0; ks < 2; ++ks) {
      short8 af[4], bfr[4];
      #pragma unroll
      for (int mi = 0; mi < 4; ++mi) {
        int row = wm * 64 + mi * 16 + col16;
        int slot = (ks * 4 + krow) ^ (row & 7);
        af[mi] = *(const short8*)&As[row * 64 + slot * 8];
      }
      #pragma unroll
      for (int nj = 0; nj < 4; ++nj) {
        int row = wn * 64 + nj * 16 + col16;
        int slot = (ks * 4 + krow) ^ (row & 7);
        bfr[nj] = *(const short8*)&Bs[row * 64 + slot * 8];
      }
      #pragma unroll
      for (int mi = 0; mi < 4; ++mi)
        #pragma unroll
        for (int nj = 0; nj < 4; ++nj)
          acc[mi][nj] = __builtin_amdgcn_mfma_f32_16x16x32_bf16(
              af[mi], bfr[nj], acc[mi][nj], 0, 0, 0);
    }
    __syncthreads();
  }

  ushort* obufT = elds;
  #pragma unroll
  for (int mi = 0; mi < 4; ++mi)
    #pragma unroll
    for (int nj = 0; nj < 4; ++nj) {
      int mcol = wn * 64 + nj * 16 + col16;
      int lrow = wm * 64 + mi * 16 + krow * 4;
      bfx4 h;
      #pragma unroll
      for (int r = 0; r < 4; ++r) h[r] = f2bf(acc[mi][nj][r]);
      *(bfx4*)&obufT[mcol * 132 + lrow] = h;
    }
  SBAR();
  {
    int lL = tid & 63, mg = tid >> 6;
    for (int it = 0; it < 32; ++it) {
      int mL = mg * 32 + it;
      int gm = j0 + mL;
      if (gm >= 197) break;
      #pragma unroll
      for (int lh = 0; lh < 2; ++lh) {
        int l = lh * 64 + lL;
        int gl = i0 + l;
        if (gl < 224)
          ETb[bz * 50432L + (long)gm * 256 + gl] =
              (gl < 197) ? obufT[mL * 132 + l] : (ushort)0;
      }
    }
  }
  {
    int mL = tid & 63, lg = tid >> 6;
    for (int it = 0; it < 32; ++it) {
      int lL = lg * 32 + it;
      int gl = i0 + lL;
      if (gl >= 197) break;
      #pragma unroll
      for (int mh = 0; mh < 2; ++mh) {
        int m = mh * 64 + mL;
        int gm = j0 + m;
        if (gm < 224)
          Eb[bz * 50432L + (long)gl * 256 + gm] =
              (gm < 197) ? obufT[m * 132 + lL] : (ushort)0;
      }
    }
  }
}

// ---------------- fused att-logit GEMM + column softmax, counted vmcnt -------
__global__ __launch_bounds__(256) void att_gemm(
    const ushort* __restrict__ Wl0, const ushort* __restrict__ Wl1,
    const ushort* __restrict__ E0, const ushort* __restrict__ E1,
    const float* __restrict__ bl0, const float* __restrict__ bl1,
    ushort* __restrict__ a0, ushort* __restrict__ a1out)
{
  __shared__ ushort Aws[2][208 * 32];
  __shared__ ushort Bws[2][64 * 32];
  __shared__ float blds[208];
  const int which = blockIdx.z;
  const int bz = blockIdx.y;
  const ushort* Wl = which ? Wl1 : Wl0;
  const ushort* Bb = (which ? E1 : E0) + 50432L * bz;
  const float* bl = which ? bl1 : bl0;
  ushort* aout = which ? a1out : a0;
  const int l0 = blockIdx.x * 64;
  const int tid = threadIdx.x, wave = tid >> 6, lane = tid & 63;
  const int col16 = lane & 15, kq = lane >> 4;

  if (tid < 208) blds[tid] = (tid < 197) ? bl[tid] : 0.f;

  f32x4 acc[13] = {};

  auto stage = [&](int buf, int k0) {
    const int lrow = lane >> 2, s = lane & 3;
    #pragma unroll
    for (int c0 = 0; c0 < 5; ++c0) {
      int c = wave + c0 * 4;
      if (c >= 17) break;
      if (c < 13) {
        int row = c * 16 + lrow;
        int gr = row < 197 ? row : 196;
        int kc = s ^ swz4(row);
        gload16(Wl + (long)gr * 256 + k0 + kc * 8,
                (char*)(&Aws[buf][0]) + c * 1024 + lane * 16);
      } else {
        int row = (c - 13) * 16 + lrow;
        int gl = l0 + row; if (gl > 196) gl = 196;
        int kc = s ^ swz4(row);
        gload16(Bb + (long)gl * 256 + k0 + kc * 8,
                (char*)(&Bws[buf][0]) + (c - 13) * 1024 + lane * 16);
      }
    }
  };

  stage(0, 0);
  for (int t = 0; t < 7; ++t) {
    int cur = t & 1;
    if (t + 1 < 7) {
      stage(cur ^ 1, (t + 1) * 32);
      if (wave == 0) VM_WAIT(5); else VM_WAIT(4);
    } else {
      VM_WAIT(0);
    }
    SBAR();
    int brow = wave * 16 + col16;
    short8 bf = *(const short8*)((const char*)(&Bws[cur][0]) +
                                 brow * 64 + ((kq ^ swz4(brow)) << 4));
    #pragma unroll
    for (int j = 0; j < 13; ++j) {
      int arow = j * 16 + col16;
      short8 af = *(const short8*)((const char*)(&Aws[cur][0]) +
                                   arow * 64 + ((kq ^ swz4(arow)) << 4));
      acc[j] = __builtin_amdgcn_mfma_f32_16x16x32_bf16(af, bf, acc[j], 0, 0, 0);
    }
    SBAR();
  }

  const int c = l0 + wave * 16 + col16;
  float mx = -INFINITY;
  #pragma unroll
  for (int j = 0; j < 13; ++j)
    #pragma unroll
    for (int r = 0; r < 4; ++r) {
      int m = j * 16 + kq * 4 + r;
      float v = acc[j][r] + blds[m];
      v = (m < 197) ? v : -INFINITY;
      acc[j][r] = v;
      mx = fmaxf(mx, v);
    }
  mx = fmaxf(mx, __shfl_xor(mx, 16));
  mx = fmaxf(mx, __shfl_xor(mx, 32));
  float s = 0.f;
  #pragma unroll
  for (int j = 0; j < 13; ++j)
    #pragma unroll
    for (int r = 0; r < 4; ++r) {
      int m = j * 16 + kq * 4 + r;
      float e = (m < 197) ? __expf(acc[j][r] - mx) : 0.f;
      acc[j][r] = e;
      s += e;
    }
  s += __shfl_xor(s, 16);
  s += __shfl_xor(s, 32);
  const float inv = 1.f / s;
  ushort* ab = aout + 50432L * bz;
  #pragma unroll
  for (int j = 0; j < 13; ++j)
    #pragma unroll
    for (int r = 0; r < 4; ++r) {
      int m = j * 16 + kq * 4 + r;
      if (m < 197)
        ab[(long)m * 256 + c] = (c < 197) ? f2bf(acc[j][r] * inv) : (ushort)0;
    }
}

// ---------------- fused v+out GEMM: per (which, batch, 64-d tile) ------------
// phase1: V[64][224] = Wv_tile @ src_b^T (K=768) -> LDS bf16 (stride 232)
// phase2: out[64][m] = gamma * V @ att_b^T (K=224) + resid, bounce-v2 drain.
// LDS: p1 A dbuf @0/@4096; p1 B dbuf @8192/@22528; p2 B dbuf @0/@14336;
//      V @28672 (64*232*2 = 29696 B); total 58368 B -> 2 blocks/CU.
__global__ __launch_bounds__(256) void vfused_gemm(
    const ushort* __restrict__ Wv0, const ushort* __restrict__ Wv1,
    const ushort* __restrict__ S0, const ushort* __restrict__ S1,
    const float* __restrict__ bv0, const float* __restrict__ bv1,
    const ushort* __restrict__ At0, const ushort* __restrict__ At1,
    const ushort* __restrict__ R0, const ushort* __restrict__ R1,
    const float* __restrict__ g0, const float* __restrict__ g1,
    float* __restrict__ C0, float* __restrict__ C1,
    int Bc)
{
  __shared__ __align__(16) char lds[58368];
  const int per = 12 * Bc;
  int bid = blockIdx.x;
  const int which = bid / per;
  bid -= which * per;
  int dtile, b;
  if ((Bc & 7) == 0) {
    int xcd = bid & 7, sid = bid >> 3;
    dtile = sid % 12;
    b = (sid / 12) * 8 + xcd;        // 12 d-tiles of a batch share one XCD
  } else {
    dtile = bid % 12;
    b = bid / 12;
  }
  const ushort* Wv = (which ? Wv1 : Wv0) + (long)(dtile * 64) * 768;
  const ushort* Sb = (which ? S1 : S0) + (long)b * 197 * 768;
  const float* bv = which ? bv1 : bv0;
  const ushort* attb = (which ? At1 : At0) + (long)b * 50432;
  const ushort* resid = which ? R1 : R0;
  const float g = (which ? g1 : g0)[0];
  float* C = which ? C1 : C0;

  const int tid = threadIdx.x, wave = tid >> 6, lane = tid & 63;
  const int wr = wave >> 1, wc = wave & 1;   // 2x2: 32-d x 112-col wave tiles
  const int col16 = lane & 15, kq = lane >> 4;

  f32x4 acc[2][7] = {};

  // ---- phase 1: K=768, BK=32, 24 steps ----
  auto stage1 = [&](int buf, int k0) {
    const int lrow = lane >> 2, s = lane & 3;
    #pragma unroll
    for (int c0 = 0; c0 < 5; ++c0) {
      int c = wave + c0 * 4;
      if (c >= 18) break;                  // waves 0,1: 5 chunks; 2,3: 4
      if (c < 4) {
        int row = c * 16 + lrow;
        int kc = s ^ swz4(row);
        gload16(Wv + (long)row * 768 + k0 + kc * 8,
                lds + buf * 4096 + c * 1024 + lane * 16);
      } else {
        int j = (c - 4) * 16 + lrow;
        int gr = j < 197 ? j : 196;
        int kc = s ^ swz4(j);
        gload16(Sb + (long)gr * 768 + k0 + kc * 8,
                lds + 8192 + buf * 14336 + (c - 4) * 1024 + lane * 16);
      }
    }
  };

  stage1(0, 0);
  for (int t = 0; t < 24; ++t) {
    int cur = t & 1;
    if (t + 1 < 24) {
      stage1(cur ^ 1, (t + 1) << 5);
      if (wave < 2) VM_WAIT(5); else VM_WAIT(4);
    } else {
      VM_WAIT(0);
    }
    SBAR();
    short8 af[2];
    #pragma unroll
    for (int mi = 0; mi < 2; ++mi) {
      int ar = wr * 32 + mi * 16 + col16;
      af[mi] = *(const short8*)(lds + cur * 4096 + ar * 64 + ((kq ^ swz4(ar)) << 4));
    }
    #pragma unroll
    for (int nj = 0; nj < 7; ++nj) {
      int br = wc * 112 + nj * 16 + col16;
      short8 bf = *(const short8*)(lds + 8192 + cur * 14336 +
                                   br * 64 + ((kq ^ swz4(br)) << 4));
      #pragma unroll
      for (int mi = 0; mi < 2; ++mi)
        acc[mi][nj] = __builtin_amdgcn_mfma_f32_16x16x32_bf16(
            af[mi], bf, acc[mi][nj], 0, 0, 0);
    }
    SBAR();
  }

  // write V (+bias) as bf16 to VLDS [64][stride 232]; cols>=197 hold junk
  // but att cols [197,256) are zero, so phase-2 products vanish.
  ushort* vlds = (ushort*)(lds + 28672);
  #pragma unroll
  for (int mi = 0; mi < 2; ++mi)
    #pragma unroll
    for (int r = 0; r < 4; ++r) {
      int dl = wr * 32 + mi * 16 + kq * 4 + r;
      float bvv = bv[dtile * 64 + dl];
      #pragma unroll
      for (int nj = 0; nj < 7; ++nj) {
        int l = wc * 112 + nj * 16 + col16;
        vlds[dl * 232 + l] = f2bf(acc[mi][nj][r] + bvv);
      }
    }
  LGKM_WAIT();
  SBAR();

  // ---- phase 2: K=224, BK=32, 7 steps ----
  #pragma unroll
  for (int mi = 0; mi < 2; ++mi)
    #pragma unroll
    for (int nj = 0; nj < 7; ++nj)
      acc[mi][nj] = (f32x4){0.f, 0.f, 0.f, 0.f};

  auto stage2 = [&](int buf, int k0) {
    const int lrow = lane >> 2, s = lane & 3;
    #pragma unroll
    for (int c0 = 0; c0 < 4; ++c0) {
      int c = wave + c0 * 4;
      if (c >= 14) break;                  // waves 0,1: 4 chunks; 2,3: 3
      int m = c * 16 + lrow;
      int gm = m < 197 ? m : 196;
      int kc = s ^ swz4(m);
      gload16(attb + (long)gm * 256 + k0 + kc * 8,
              lds + buf * 14336 + c * 1024 + lane * 16);
    }
  };

  stage2(0, 0);
  for (int t = 0; t < 7; ++t) {
    int cur = t & 1;
    if (t + 1 < 7) {
      stage2(cur ^ 1, (t + 1) << 5);
      if (wave < 2) VM_WAIT(4); else VM_WAIT(3);
    } else {
      VM_WAIT(0);
    }
    SBAR();
    const int k0 = t << 5;
    short8 af[2];
    #pragma unroll
    for (int mi = 0; mi < 2; ++mi) {
      int ar = wr * 32 + mi * 16 + col16;
      af[mi] = *(const short8*)((const char*)vlds + ar * 464 + k0 * 2 + kq * 16);
    }
    #pragma unroll
    for (int nj = 0; nj < 7; ++nj) {
      int br = wc * 112 + nj * 16 + col16;
      short8 bf = *(const short8*)(lds + cur * 14336 +
                                   br * 64 + ((kq ^ swz4(br)) << 4));
      #pragma unroll
      for (int mi = 0; mi < 2; ++mi)
        acc[mi][nj] = __builtin_amdgcn_mfma_f32_16x16x32_bf16(
            af[mi], bf, acc[mi][nj], 0, 0, 0);
    }
    SBAR();
  }

  // bounce-v2 drain: obufT [112 m-cols][stride 68 d-rows] bf16
  ushort* obufT = (ushort*)lds;
  #pragma unroll 1
  for (int c = 0; c < 2; ++c) {
    if (wc == c) {
      #pragma unroll
      for (int mi = 0; mi < 2; ++mi)
        #pragma unroll
        for (int nj = 0; nj < 7; ++nj) {
          int colL = nj * 16 + col16;
          int row = wr * 32 + mi * 16 + kq * 4;
          bfx4 h;
          #pragma unroll
          for (int r = 0; r < 4; ++r) h[r] = f2bf(g * acc[mi][nj][r]);
          *(bfx4*)&obufT[colL * 68 + row] = h;
        }
    }
    SBAR();
    {
      int colL = tid & 127, rg = tid >> 7;
      int ncols = 197 - c * 112; if (ncols > 112) ncols = 112;
      if (colL < ncols) {
        int gcol = c * 112 + colL;
        #pragma unroll 4
        for (int it = 0; it < 32; ++it) {
          int row = rg * 32 + it;
          long ci = (long)b * 151296 + (long)(dtile * 64 + row) * 197 + gcol;
          C[ci] = bf2f(obufT[colL * 68 + row]) + bf2f(resid[ci]);
        }
      }
    }
    SBAR();
  }
}

// ---------------- merged small helpers ---------------------------------------
__global__ void fuse_bias2(const float* __restrict__ Wks,
                           const float* __restrict__ bk1, const float* __restrict__ bk2,
                           const float* __restrict__ bks,
                           float* __restrict__ bf1, float* __restrict__ bf2) {
  int c = threadIdx.x;
  if (c >= 192) return;
  const float* bk = (c < 96) ? bk1 : bk2;
  float* bf = (c < 96) ? bf1 : bf2;
  int cc = (c < 96) ? c : c - 96;
  float s = bks[cc];
  for (int e = 0; e < 96; ++e) s += Wks[cc * 96 + e] * bk[e];
  bf[cc] = s;
}

__global__ __launch_bounds__(256) void conv_weights(
    const float* __restrict__ Wf1, const float* __restrict__ Wf2,
    const float* __restrict__ Wv1, const float* __restrict__ Wv2,
    const float* __restrict__ Wl1, const float* __restrict__ Wl2,
    ushort* __restrict__ Wf1b, ushort* __restrict__ Wf2b,
    ushort* __restrict__ Wv1b, ushort* __restrict__ Wv2b,
    ushort* __restrict__ Wl1b, ushort* __restrict__ Wl2b)
{
  const long total = 147456 + 1179648 + 100864;
  long stride = (long)gridDim.x * blockDim.x;
  for (long i = (long)blockIdx.x * blockDim.x + threadIdx.x; i < total; i += stride) {
    if (i < 147456) {
      long j = i;
      if (j < 73728) Wf1b[j] = f2bf(Wf1[j]);
      else Wf2b[j - 73728] = f2bf(Wf2[j - 73728]);
    } else if (i < 147456 + 1179648) {
      long j = i - 147456;
      if (j < 589824) Wv1b[j] = f2bf(Wv1[j]);
      else Wv2b[j - 589824] = f2bf(Wv2[j - 589824]);
    } else {
      long j = i - 147456 - 1179648;
      int w2 = j >= 50432;
      if (w2) j -= 50432;
      int r = (int)(j >> 8), cc = (int)(j & 255);
      const float* s = w2 ? Wl2 : Wl1;
      ushort* d = w2 ? Wl2b : Wl1b;
      d[j] = (cc < 197) ? f2bf(s[(long)r * 197 + cc]) : (ushort)0;
    }
  }
}

__global__ __launch_bounds__(256) void conv_xy(const float* __restrict__ x,
                                               const float* __restrict__ y,
                                               ushort* __restrict__ xb,
                                               ushort* __restrict__ yb, long n8) {
  long i = (long)blockIdx.x * blockDim.x + threadIdx.x;
  long stride = (long)gridDim.x * blockDim.x;
  for (; i < 2 * n8; i += stride) {
    const float* s = (i < n8) ? x : y;
    ushort* d = (i < n8) ? xb : yb;
    long j = (i < n8) ? i : i - n8;
    float4 a = ((const float4*)s)[2 * j];
    float4 b = ((const float4*)s)[2 * j + 1];
    ushort8 o;
    o[0] = f2bf(a.x); o[1] = f2bf(a.y); o[2] = f2bf(a.z); o[3] = f2bf(a.w);
    o[4] = f2bf(b.x); o[5] = f2bf(b.y); o[6] = f2bf(b.z); o[7] = f2bf(b.w);
    *(ushort8*)&d[j * 8] = o;
  }
}

// ---------------- launcher ---------------------------------------------------
extern "C" void kernel_launch(void* const* d_in, const int* in_sizes, int n_in,
                              void* d_out, int out_size, void* d_ws, size_t ws_size,
                              hipStream_t stream) {
  const float* x   = (const float*)d_in[0];
  const float* y   = (const float*)d_in[1];
  const float* Wk1 = (const float*)d_in[2];
  const float* bk1 = (const float*)d_in[3];
  const float* Wk2 = (const float*)d_in[4];
  const float* bk2 = (const float*)d_in[5];
  const float* Wks = (const float*)d_in[6];
  const float* bks = (const float*)d_in[7];
  const float* Wl1 = (const float*)d_in[8];
  const float* bl1 = (const float*)d_in[9];
  const float* Wl2 = (const float*)d_in[10];
  const float* bl2 = (const float*)d_in[11];
  const float* Wv1 = (const float*)d_in[12];
  const float* bv1 = (const float*)d_in[13];
  const float* Wv2 = (const float*)d_in[14];
  const float* bv2 = (const float*)d_in[15];
  const float* gamma1 = (const float*)d_in[16];
  const float* gamma2 = (const float*)d_in[17];
  float* out = (float*)d_out;

  const int B = 256, L = 197, D = 768;
  const long LD = (long)L * D;     // 151296

  const size_t staticBytes = 3446784;
  const size_t perB = 605184 + 75648 + 100864 + 201728 + 201728;  // 1185152
  int Bc = 256;
  while (Bc > 8 && staticBytes + (size_t)Bc * perB > ws_size) Bc >>= 1;

  char* p = (char*)d_ws;
  auto carve = [&](size_t bytes) { char* r = p; p += bytes; return r; };
  float*  Wf1   = (float*)carve(73728 * 4);
  float*  Wf2   = (float*)carve(73728 * 4);
  float*  bf1   = (float*)carve(512);
  float*  bf2   = (float*)carve(512);
  ushort* Wv1b  = (ushort*)carve(589824 * 2);
  ushort* Wv2b  = (ushort*)carve(589824 * 2);
  ushort* Wf1b  = (ushort*)carve(73728 * 2);
  ushort* Wf2b  = (ushort*)carve(73728 * 2);
  ushort* Wl1b  = (ushort*)carve(50432 * 2);
  ushort* Wl2b  = (ushort*)carve(50432 * 2);
  ushort* xb    = (ushort*)carve((size_t)Bc * LD * 2);
  ushort* yb    = (ushort*)carve((size_t)Bc * LD * 2);
  ushort* k1    = (ushort*)carve((size_t)Bc * 18912 * 2);
  ushort* k2    = (ushort*)carve((size_t)Bc * 18912 * 2);
  ushort* EA1   = (ushort*)carve((size_t)Bc * 25216 * 2);
  ushort* EA2   = (ushort*)carve((size_t)Bc * 25216 * 2);
  ushort* Eb    = (ushort*)carve((size_t)Bc * 50432 * 2);
  ushort* ETbuf = (ushort*)carve((size_t)Bc * 50432 * 2);
  ushort* a1    = (ushort*)carve((size_t)Bc * 50432 * 2);
  ushort* a2    = (ushort*)carve((size_t)Bc * 50432 * 2);

  dim3 blk(256);

  gemm_generic<<<dim3(12, 2, 2), blk, 0, stream>>>(Wks, Wk1, Wk2, Wf1, Wf2,
      96, 768, 96, 96, 1, 1, 768, 768);
  fuse_bias2<<<1, 192, 0, stream>>>(Wks, bk1, bk2, bks, bf1, bf2);
  conv_weights<<<dim3(1024), blk, 0, stream>>>(Wf1, Wf2, Wv1, Wv2, Wl1, Wl2,
      Wf1b, Wf2b, Wv1b, Wv2b, Wl1b, Wl2b);

  for (int c0 = 0; c0 < B; c0 += Bc) {
    const float* xc = x + (long)c0 * LD;
    const float* yc = y + (long)c0 * LD;
    const int Mr = Bc * L;
    const int gym = (Mr + 127) / 128;

    conv_xy<<<dim3(2048), blk, 0, stream>>>(xc, yc, xb, yb, (long)Bc * LD / 8);

    mfma_gemm<<<dim3(1, gym, 2), blk, 0, stream>>>(xb, yb, Wf1b, Wf2b, bf1, bf2,
        k1, k2, Mr, 96, 768, 768, 768, 96);

    transpose_k<<<dim3(7, 4, 2 * Bc), blk, 0, stream>>>(k1, k2, EA1, EA2, Bc);

    energy_mfma<<<dim3(2, 2, Bc), blk, 0, stream>>>(EA1, EA2, Eb, ETbuf);

    att_gemm<<<dim3(4, Bc, 2), blk, 0, stream>>>(Wl1b, Wl2b, Eb, ETbuf,
        bl1, bl2, a1, a2);

    // fused v + out (replaces vbig_gemm + vout_gemm; no vT round-trip)
    vfused_gemm<<<dim3(2 * 12 * Bc), blk, 0, stream>>>(
        Wv2b, Wv1b, yb, xb, bv2, bv1, a1, a2, xb, yb, gamma1, gamma2,
        out + (long)c0 * LD, out + (long)B * LD + (long)c0 * LD, Bc);
  }
}

// Round 19
// 603.560 us; speedup vs baseline: 1.1528x; 1.0549x over previous
//
#include <hip/hip_runtime.h>
#include <math.h>

typedef unsigned short ushort;
typedef __attribute__((ext_vector_type(4))) unsigned short bfx4;
typedef __attribute__((ext_vector_type(8))) short short8;
typedef __attribute__((ext_vector_type(8))) unsigned short ushort8;
typedef __attribute__((ext_vector_type(4))) float f32x4;
typedef unsigned int u32;

#define VM_WAIT(N) asm volatile("s_waitcnt vmcnt(" #N ")" ::: "memory")
#define SBAR() asm volatile("s_barrier" ::: "memory")

__device__ __forceinline__ int swz4(int row) {
  return (row & 3) ^ ((row >> 2) & 3);
}

__device__ __forceinline__ ushort f2bf(float f) {
  u32 u = __float_as_uint(f);
  return (ushort)((u + 0x7FFF + ((u >> 16) & 1)) >> 16);
}
__device__ __forceinline__ float bf2f(ushort u) {
  u32 v = ((u32)u) << 16;
  return __uint_as_float(v);
}

__device__ __forceinline__ void gload16(const void* g, void* l) {
  __builtin_amdgcn_global_load_lds(
      (const __attribute__((address_space(1))) u32*)g,
      (__attribute__((address_space(3))) u32*)l, 16, 0, 0);
}

// ---------------- fp32 VALU GEMM (static Wf GEMMs only), z=which -------------
#define BKK 32
#define LDSP 68
__global__ __launch_bounds__(256) void gemm_generic(
    const float* __restrict__ A, const float* __restrict__ Bm, const float* __restrict__ Bm2,
    float* __restrict__ C, float* __restrict__ C2,
    int M, int N, int K, long sAi, long sAk, long sBj, long sBk, long sCi)
{
  __shared__ __align__(16) float lds_a[BKK * LDSP];
  __shared__ __align__(16) float lds_b[BKK * LDSP];
  const float* Bb = blockIdx.z ? Bm2 : Bm;
  float* Cc = blockIdx.z ? C2 : C;
  const int i0 = blockIdx.y * 64;
  const int j0 = blockIdx.x * 64;
  const int tid = threadIdx.x;
  const int tx = tid & 15, ty = tid >> 4;
  float acc[4][4] = {};
  for (int k0 = 0; k0 < K; k0 += BKK) {
    for (int idx = tid; idx < BKK * 64; idx += 256) {
      int kk = idx & (BKK - 1), ii = idx >> 5;
      int gi = i0 + ii, gk = k0 + kk;
      lds_a[kk * LDSP + ii] = (gi < M && gk < K) ? A[(long)gi * sAi + (long)gk * sAk] : 0.f;
    }
    for (int idx = tid; idx < BKK * 64; idx += 256) {
      int kk = idx & (BKK - 1), jj = idx >> 5;
      int gj = j0 + jj, gk = k0 + kk;
      lds_b[kk * LDSP + jj] = (gj < N && gk < K) ? Bb[(long)gj * sBj + (long)gk * sBk] : 0.f;
    }
    __syncthreads();
    #pragma unroll
    for (int kk = 0; kk < BKK; ++kk) {
      const float4 a4 = *reinterpret_cast<const float4*>(&lds_a[kk * LDSP + ty * 4]);
      const float4 b4 = *reinterpret_cast<const float4*>(&lds_b[kk * LDSP + tx * 4]);
      const float av[4] = {a4.x, a4.y, a4.z, a4.w};
      const float bv[4] = {b4.x, b4.y, b4.z, b4.w};
      #pragma unroll
      for (int a = 0; a < 4; ++a)
        #pragma unroll
        for (int b = 0; b < 4; ++b)
          acc[a][b] = fmaf(av[a], bv[b], acc[a][b]);
    }
    __syncthreads();
  }
  for (int a = 0; a < 4; ++a) {
    int gi = i0 + ty * 4 + a;
    if (gi >= M) continue;
    for (int b = 0; b < 4; ++b) {
      int gj = j0 + tx * 4 + b;
      if (gj >= N) continue;
      Cc[(long)gi * sCi + gj] = acc[a][b];
    }
  }
}

// ---------------- merged k GEMM: 128x128 tile, bf16 out, z=which -------------
__global__ __launch_bounds__(256) void mfma_gemm(
    const ushort* __restrict__ A0, const ushort* __restrict__ A1,
    const ushort* __restrict__ B0, const ushort* __restrict__ B1,
    const float* __restrict__ bias0, const float* __restrict__ bias1,
    ushort* __restrict__ C0, ushort* __restrict__ C1,
    int M, int N, int K, long sAi, long sBj, long sCi)
{
  __shared__ ushort As[128 * 64];
  __shared__ ushort Bs[128 * 64];
  const int which = blockIdx.z;
  const ushort* Ab = which ? A1 : A0;
  const ushort* Bb = which ? B1 : B0;
  const float* bias = which ? bias1 : bias0;
  ushort* C = which ? C1 : C0;
  const int i0 = blockIdx.y * 128;
  const int j0 = blockIdx.x * 128;
  const int tid = threadIdx.x;
  const int wave = tid >> 6, lane = tid & 63;
  const int wm = wave >> 1, wn = wave & 1;
  const int col16 = lane & 15, krow = lane >> 4;

  f32x4 acc[4][4] = {};

  for (int k0 = 0; k0 < K; k0 += 64) {
    #pragma unroll
    for (int it = 0; it < 4; ++it) {
      int chunk = it * 256 + wave * 64 + lane;
      int row = chunk >> 3, s = chunk & 7;
      int kc = s ^ (row & 7);
      int gi = i0 + row; if (gi >= M) gi = M - 1;
      gload16(Ab + (long)gi * sAi + k0 + kc * 8, &As[chunk * 8]);
    }
    #pragma unroll
    for (int it = 0; it < 4; ++it) {
      int chunk = it * 256 + wave * 64 + lane;
      int row = chunk >> 3, s = chunk & 7;
      int kc = s ^ (row & 7);
      int gj = j0 + row; if (gj >= N) gj = N - 1;
      gload16(Bb + (long)gj * sBj + k0 + kc * 8, &Bs[chunk * 8]);
    }
    __syncthreads();
    #pragma unroll
    for (int ks = 0; ks < 2; ++ks) {
      short8 af[4], bfr[4];
      #pragma unroll
      for (int mi = 0; mi < 4; ++mi) {
        int row = wm * 64 + mi * 16 + col16;
        int slot = (ks * 4 + krow) ^ (row & 7);
        af[mi] = *(const short8*)&As[row * 64 + slot * 8];
      }
      #pragma unroll
      for (int nj = 0; nj < 4; ++nj) {
        int row = wn * 64 + nj * 16 + col16;
        int slot = (ks * 4 + krow) ^ (row & 7);
        bfr[nj] = *(const short8*)&Bs[row * 64 + slot * 8];
      }
      #pragma unroll
      for (int mi = 0; mi < 4; ++mi)
        #pragma unroll
        for (int nj = 0; nj < 4; ++nj)
          acc[mi][nj] = __builtin_amdgcn_mfma_f32_16x16x32_bf16(
              af[mi], bfr[nj], acc[mi][nj], 0, 0, 0);
    }
    __syncthreads();
  }

  const int r0 = krow * 4;
  #pragma unroll
  for (int mi = 0; mi < 4; ++mi) {
    int gi0 = i0 + wm * 64 + mi * 16 + r0;
    #pragma unroll
    for (int nj = 0; nj < 4; ++nj) {
      int gj = j0 + wn * 64 + nj * 16 + col16;
      f32x4 a = acc[mi][nj];
      #pragma unroll
      for (int r = 0; r < 4; ++r) {
        int gi = gi0 + r;
        if (gi >= M || gj >= N) continue;
        C[(long)gi * sCi + gj] = f2bf(a[r] + bias[gj]);
      }
    }
  }
}

// ---------------- transpose k (bf16): per batch [96][197]-view -> [197][128] -
__global__ __launch_bounds__(256) void transpose_k(
    const ushort* __restrict__ k1, const ushort* __restrict__ k2,
    ushort* __restrict__ EA1, ushort* __restrict__ EA2, int Bc)
{
  __shared__ ushort tile[32][33];
  int z = blockIdx.z;
  int which = (z >= Bc) ? 1 : 0;
  int b = which ? z - Bc : z;
  const ushort* src = (which ? k2 : k1) + (long)b * 18912;
  ushort* dst = (which ? EA2 : EA1) + (long)b * 25216;
  int l0 = blockIdx.x * 32, c0 = blockIdx.y * 32;
  int tx = threadIdx.x & 31, ty = threadIdx.x >> 5;
  for (int r = ty; r < 32; r += 8) {
    int c = c0 + r, l = l0 + tx;
    tile[r][tx] = (c < 96 && l < 197) ? src[(long)c * 197 + l] : (ushort)0;
  }
  __syncthreads();
  for (int r = ty; r < 32; r += 8) {
    int l = l0 + r, c = c0 + tx;
    if (l < 197 && c < 128) dst[(long)l * 128 + c] = tile[tx][r];
  }
}

// ---------------- energy GEMM (MFMA): E = EA1 . EA2^T, dual bf16 write -------
__global__ __launch_bounds__(256) void energy_mfma(
    const ushort* __restrict__ EA1, const ushort* __restrict__ EA2,
    ushort* __restrict__ Eb, ushort* __restrict__ ETb)
{
  __shared__ ushort elds[16896];     // staging 2x8192; bounce [128][132]
  ushort* As = elds;
  ushort* Bs = elds + 8192;
  const int bz = blockIdx.z;
  const ushort* Ab = EA1 + 25216L * bz;
  const ushort* Bb = EA2 + 25216L * bz;
  const int i0 = blockIdx.y * 128;   // l
  const int j0 = blockIdx.x * 128;   // m
  const int tid = threadIdx.x;
  const int wave = tid >> 6, lane = tid & 63;
  const int wm = wave >> 1, wn = wave & 1;
  const int col16 = lane & 15, krow = lane >> 4;

  f32x4 acc[4][4] = {};

  for (int k0 = 0; k0 < 128; k0 += 64) {
    #pragma unroll
    for (int it = 0; it < 4; ++it) {
      int chunk = it * 256 + wave * 64 + lane;
      int row = chunk >> 3, s = chunk & 7;
      int kc = s ^ (row & 7);
      int gi = i0 + row; if (gi > 196) gi = 196;
      gload16(Ab + (long)gi * 128 + k0 + kc * 8, &As[chunk * 8]);
    }
    #pragma unroll
    for (int it = 0; it < 4; ++it) {
      int chunk = it * 256 + wave * 64 + lane;
      int row = chunk >> 3, s = chunk & 7;
      int kc = s ^ (row & 7);
      int gj = j0 + row; if (gj > 196) gj = 196;
      gload16(Bb + (long)gj * 128 + k0 + kc * 8, &Bs[chunk * 8]);
    }
    __syncthreads();
    #pragma unroll
    for (int ks = 0; ks < 2; ++ks) {
      short8 af[4], bfr[4];
      #pragma unroll
      for (int mi = 0; mi < 4; ++mi) {
        int row = wm * 64 + mi * 16 + col16;
        int slot = (ks * 4 + krow) ^ (row & 7);
        af[mi] = *(const short8*)&As[row * 64 + slot * 8];
      }
      #pragma unroll
      for (int nj = 0; nj < 4; ++nj) {
        int row = wn * 64 + nj * 16 + col16;
        int slot = (ks * 4 + krow) ^ (row & 7);
        bfr[nj] = *(const short8*)&Bs[row * 64 + slot * 8];
      }
      #pragma unroll
      for (int mi = 0; mi < 4; ++mi)
        #pragma unroll
        for (int nj = 0; nj < 4; ++nj)
          acc[mi][nj] = __builtin_amdgcn_mfma_f32_16x16x32_bf16(
              af[mi], bfr[nj], acc[mi][nj], 0, 0, 0);
    }
    __syncthreads();
  }

  ushort* obufT = elds;
  #pragma unroll
  for (int mi = 0; mi < 4; ++mi)
    #pragma unroll
    for (int nj = 0; nj < 4; ++nj) {
      int mcol = wn * 64 + nj * 16 + col16;
      int lrow = wm * 64 + mi * 16 + krow * 4;
      bfx4 h;
      #pragma unroll
      for (int r = 0; r < 4; ++r) h[r] = f2bf(acc[mi][nj][r]);
      *(bfx4*)&obufT[mcol * 132 + lrow] = h;
    }
  __syncthreads();
  {
    int lL = tid & 63, mg = tid >> 6;
    for (int it = 0; it < 32; ++it) {
      int mL = mg * 32 + it;
      int gm = j0 + mL;
      if (gm >= 197) break;
      #pragma unroll
      for (int lh = 0; lh < 2; ++lh) {
        int l = lh * 64 + lL;
        int gl = i0 + l;
        if (gl < 224)
          ETb[bz * 50432L + (long)gm * 256 + gl] =
              (gl < 197) ? obufT[mL * 132 + l] : (ushort)0;
      }
    }
  }
  {
    int mL = tid & 63, lg = tid >> 6;
    for (int it = 0; it < 32; ++it) {
      int lL = lg * 32 + it;
      int gl = i0 + lL;
      if (gl >= 197) break;
      #pragma unroll
      for (int mh = 0; mh < 2; ++mh) {
        int m = mh * 64 + mL;
        int gm = j0 + m;
        if (gm < 224)
          Eb[bz * 50432L + (long)gl * 256 + gm] =
              (gm < 197) ? obufT[m * 132 + lL] : (ushort)0;
      }
    }
  }
}

// ---------------- fused att-logit GEMM + column softmax, counted vmcnt -------
__global__ __launch_bounds__(256) void att_gemm(
    const ushort* __restrict__ Wl0, const ushort* __restrict__ Wl1,
    const ushort* __restrict__ E0, const ushort* __restrict__ E1,
    const float* __restrict__ bl0, const float* __restrict__ bl1,
    ushort* __restrict__ a0, ushort* __restrict__ a1out)
{
  __shared__ ushort Aws[2][208 * 32];
  __shared__ ushort Bws[2][64 * 32];
  __shared__ float blds[208];
  const int which = blockIdx.z;
  const int bz = blockIdx.y;
  const ushort* Wl = which ? Wl1 : Wl0;
  const ushort* Bb = (which ? E1 : E0) + 50432L * bz;
  const float* bl = which ? bl1 : bl0;
  ushort* aout = which ? a1out : a0;
  const int l0 = blockIdx.x * 64;
  const int tid = threadIdx.x, wave = tid >> 6, lane = tid & 63;
  const int col16 = lane & 15, kq = lane >> 4;

  if (tid < 208) blds[tid] = (tid < 197) ? bl[tid] : 0.f;

  f32x4 acc[13] = {};

  auto stage = [&](int buf, int k0) {
    const int lrow = lane >> 2, s = lane & 3;
    #pragma unroll
    for (int c0 = 0; c0 < 5; ++c0) {
      int c = wave + c0 * 4;
      if (c >= 17) break;
      if (c < 13) {
        int row = c * 16 + lrow;
        int gr = row < 197 ? row : 196;
        int kc = s ^ swz4(row);
        gload16(Wl + (long)gr * 256 + k0 + kc * 8,
                (char*)(&Aws[buf][0]) + c * 1024 + lane * 16);
      } else {
        int row = (c - 13) * 16 + lrow;
        int gl = l0 + row; if (gl > 196) gl = 196;
        int kc = s ^ swz4(row);
        gload16(Bb + (long)gl * 256 + k0 + kc * 8,
                (char*)(&Bws[buf][0]) + (c - 13) * 1024 + lane * 16);
      }
    }
  };

  stage(0, 0);
  for (int t = 0; t < 7; ++t) {
    int cur = t & 1;
    if (t + 1 < 7) {
      stage(cur ^ 1, (t + 1) * 32);
      if (wave == 0) VM_WAIT(5); else VM_WAIT(4);
    } else {
      VM_WAIT(0);
    }
    SBAR();
    int brow = wave * 16 + col16;
    short8 bf = *(const short8*)((const char*)(&Bws[cur][0]) +
                                 brow * 64 + ((kq ^ swz4(brow)) << 4));
    #pragma unroll
    for (int j = 0; j < 13; ++j) {
      int arow = j * 16 + col16;
      short8 af = *(const short8*)((const char*)(&Aws[cur][0]) +
                                   arow * 64 + ((kq ^ swz4(arow)) << 4));
      acc[j] = __builtin_amdgcn_mfma_f32_16x16x32_bf16(af, bf, acc[j], 0, 0, 0);
    }
    SBAR();
  }

  const int c = l0 + wave * 16 + col16;
  float mx = -INFINITY;
  #pragma unroll
  for (int j = 0; j < 13; ++j)
    #pragma unroll
    for (int r = 0; r < 4; ++r) {
      int m = j * 16 + kq * 4 + r;
      float v = acc[j][r] + blds[m];
      v = (m < 197) ? v : -INFINITY;
      acc[j][r] = v;
      mx = fmaxf(mx, v);
    }
  mx = fmaxf(mx, __shfl_xor(mx, 16));
  mx = fmaxf(mx, __shfl_xor(mx, 32));
  float s = 0.f;
  #pragma unroll
  for (int j = 0; j < 13; ++j)
    #pragma unroll
    for (int r = 0; r < 4; ++r) {
      int m = j * 16 + kq * 4 + r;
      float e = (m < 197) ? __expf(acc[j][r] - mx) : 0.f;
      acc[j][r] = e;
      s += e;
    }
  s += __shfl_xor(s, 16);
  s += __shfl_xor(s, 32);
  const float inv = 1.f / s;
  ushort* ab = aout + 50432L * bz;
  #pragma unroll
  for (int j = 0; j < 13; ++j)
    #pragma unroll
    for (int r = 0; r < 4; ++r) {
      int m = j * 16 + kq * 4 + r;
      if (m < 197)
        ab[(long)m * 256 + c] = (c < 197) ? f2bf(acc[j][r] * inv) : (ushort)0;
    }
}

// ---------------- fused v+out GEMM: 44032 B LDS -> 3 blocks/CU ---------------
// phase1 (K=768, dbuf, raw barriers -- r17-proven): V accumulated in regs.
// V parked @14336 stride 232 (r17-proven stride).
// phase2 (K=224, single-buf @0..14336, __syncthreads barriers).
// drain: bounce-v2 @0 with __syncthreads.
__global__ __launch_bounds__(256) void vfused_gemm(
    const ushort* __restrict__ Wv0, const ushort* __restrict__ Wv1,
    const ushort* __restrict__ S0, const ushort* __restrict__ S1,
    const float* __restrict__ bv0, const float* __restrict__ bv1,
    const ushort* __restrict__ At0, const ushort* __restrict__ At1,
    const ushort* __restrict__ R0, const ushort* __restrict__ R1,
    const float* __restrict__ g0, const float* __restrict__ g1,
    float* __restrict__ C0, float* __restrict__ C1,
    int Bc)
{
  __shared__ __align__(16) char lds[44032];
  const int per = 12 * Bc;
  int bid = blockIdx.x;
  const int which = bid / per;
  bid -= which * per;
  int dtile, b;
  if ((Bc & 7) == 0) {
    int xcd = bid & 7, sid = bid >> 3;
    dtile = sid % 12;
    b = (sid / 12) * 8 + xcd;        // 12 d-tiles of a batch share one XCD
  } else {
    dtile = bid % 12;
    b = bid / 12;
  }
  const ushort* Wv = (which ? Wv1 : Wv0) + (long)(dtile * 64) * 768;
  const ushort* Sb = (which ? S1 : S0) + (long)b * 197 * 768;
  const float* bv = which ? bv1 : bv0;
  const ushort* attb = (which ? At1 : At0) + (long)b * 50432;
  const ushort* resid = which ? R1 : R0;
  const float g = (which ? g1 : g0)[0];
  float* C = which ? C1 : C0;

  const int tid = threadIdx.x, wave = tid >> 6, lane = tid & 63;
  const int wr = wave >> 1, wc = wave & 1;   // 2x2: 32-d x 112-col wave tiles
  const int col16 = lane & 15, kq = lane >> 4;

  f32x4 acc[2][7] = {};

  // ---- phase 1: K=768, BK=32, 24 steps, double-buffered (r17-proven) ----
  auto stage1 = [&](int buf, int k0) {
    const int lrow = lane >> 2, s = lane & 3;
    #pragma unroll
    for (int c0 = 0; c0 < 5; ++c0) {
      int c = wave + c0 * 4;
      if (c >= 18) break;                  // waves 0,1: 5 chunks; 2,3: 4
      if (c < 4) {
        int row = c * 16 + lrow;
        int kc = s ^ swz4(row);
        gload16(Wv + (long)row * 768 + k0 + kc * 8,
                lds + buf * 4096 + c * 1024 + lane * 16);
      } else {
        int j = (c - 4) * 16 + lrow;
        int gr = j < 197 ? j : 196;
        int kc = s ^ swz4(j);
        gload16(Sb + (long)gr * 768 + k0 + kc * 8,
                lds + 8192 + buf * 14336 + (c - 4) * 1024 + lane * 16);
      }
    }
  };

  stage1(0, 0);
  for (int t = 0; t < 24; ++t) {
    int cur = t & 1;
    if (t + 1 < 24) {
      stage1(cur ^ 1, (t + 1) << 5);
      if (wave < 2) VM_WAIT(5); else VM_WAIT(4);
    } else {
      VM_WAIT(0);
    }
    SBAR();
    short8 af[2];
    #pragma unroll
    for (int mi = 0; mi < 2; ++mi) {
      int ar = wr * 32 + mi * 16 + col16;
      af[mi] = *(const short8*)(lds + cur * 4096 + ar * 64 + ((kq ^ swz4(ar)) << 4));
    }
    #pragma unroll
    for (int nj = 0; nj < 7; ++nj) {
      int br = wc * 112 + nj * 16 + col16;
      short8 bf = *(const short8*)(lds + 8192 + cur * 14336 +
                                   br * 64 + ((kq ^ swz4(br)) << 4));
      #pragma unroll
      for (int mi = 0; mi < 2; ++mi)
        acc[mi][nj] = __builtin_amdgcn_mfma_f32_16x16x32_bf16(
            af[mi], bf, acc[mi][nj], 0, 0, 0);
    }
    SBAR();
  }
  __syncthreads();   // full drain before LDS repurposing (compiler-visible)

  // write V (+bias) bf16 to VLDS [64][stride 232] @14336 (p1 staging is dead).
  // cols>=197 hold junk; att cols [197,256) are zero so products vanish.
  ushort* vlds = (ushort*)(lds + 14336);
  #pragma unroll
  for (int mi = 0; mi < 2; ++mi)
    #pragma unroll
    for (int r = 0; r < 4; ++r) {
      int dl = wr * 32 + mi * 16 + kq * 4 + r;
      float bvv = bv[dtile * 64 + dl];
      #pragma unroll
      for (int nj = 0; nj < 7; ++nj) {
        int l = wc * 112 + nj * 16 + col16;
        vlds[dl * 232 + l] = f2bf(acc[mi][nj][r] + bvv);
      }
    }
  __syncthreads();

  // ---- phase 2: K=224, BK=32, 7 steps, single-buffered @0..14336 ----
  #pragma unroll
  for (int mi = 0; mi < 2; ++mi)
    #pragma unroll
    for (int nj = 0; nj < 7; ++nj)
      acc[mi][nj] = (f32x4){0.f, 0.f, 0.f, 0.f};

  auto stage2 = [&](int k0) {
    const int lrow = lane >> 2, s = lane & 3;
    #pragma unroll
    for (int c0 = 0; c0 < 4; ++c0) {
      int c = wave + c0 * 4;
      if (c >= 14) break;                  // waves 0,1: 4 chunks; 2,3: 3
      int m = c * 16 + lrow;
      int gm = m < 197 ? m : 196;
      int kc = s ^ swz4(m);
      gload16(attb + (long)gm * 256 + k0 + kc * 8,
              lds + c * 1024 + lane * 16);
    }
  };

  for (int t = 0; t < 7; ++t) {
    stage2(t << 5);
    __syncthreads();   // compiler-ordered: drains vmcnt before barrier
    const int k0 = t << 5;
    short8 af[2];
    #pragma unroll
    for (int mi = 0; mi < 2; ++mi) {
      int ar = wr * 32 + mi * 16 + col16;
      af[mi] = *(const short8*)((const char*)vlds + ar * 464 + k0 * 2 + kq * 16);
    }
    #pragma unroll
    for (int nj = 0; nj < 7; ++nj) {
      int br = wc * 112 + nj * 16 + col16;
      short8 bf = *(const short8*)(lds + br * 64 + ((kq ^ swz4(br)) << 4));
      #pragma unroll
      for (int mi = 0; mi < 2; ++mi)
        acc[mi][nj] = __builtin_amdgcn_mfma_f32_16x16x32_bf16(
            af[mi], bf, acc[mi][nj], 0, 0, 0);
    }
    __syncthreads();
  }

  // bounce-v2 drain: obufT [112 m-cols][stride 68 d-rows] bf16 @0
  ushort* obufT = (ushort*)lds;
  #pragma unroll 1
  for (int c = 0; c < 2; ++c) {
    if (wc == c) {
      #pragma unroll
      for (int mi = 0; mi < 2; ++mi)
        #pragma unroll
        for (int nj = 0; nj < 7; ++nj) {
          int colL = nj * 16 + col16;
          int row = wr * 32 + mi * 16 + kq * 4;
          bfx4 h;
          #pragma unroll
          for (int r = 0; r < 4; ++r) h[r] = f2bf(g * acc[mi][nj][r]);
          *(bfx4*)&obufT[colL * 68 + row] = h;
        }
    }
    __syncthreads();
    {
      int colL = tid & 127, rg = tid >> 7;
      int ncols = 197 - c * 112; if (ncols > 112) ncols = 112;
      if (colL < ncols) {
        int gcol = c * 112 + colL;
        #pragma unroll 4
        for (int it = 0; it < 32; ++it) {
          int row = rg * 32 + it;
          long ci = (long)b * 151296 + (long)(dtile * 64 + row) * 197 + gcol;
          C[ci] = bf2f(obufT[colL * 68 + row]) + bf2f(resid[ci]);
        }
      }
    }
    __syncthreads();
  }
}

// ---------------- merged small helpers ---------------------------------------
__global__ void fuse_bias2(const float* __restrict__ Wks,
                           const float* __restrict__ bk1, const float* __restrict__ bk2,
                           const float* __restrict__ bks,
                           float* __restrict__ bf1, float* __restrict__ bf2) {
  int c = threadIdx.x;
  if (c >= 192) return;
  const float* bk = (c < 96) ? bk1 : bk2;
  float* bf = (c < 96) ? bf1 : bf2;
  int cc = (c < 96) ? c : c - 96;
  float s = bks[cc];
  for (int e = 0; e < 96; ++e) s += Wks[cc * 96 + e] * bk[e];
  bf[cc] = s;
}

__global__ __launch_bounds__(256) void conv_weights(
    const float* __restrict__ Wf1, const float* __restrict__ Wf2,
    const float* __restrict__ Wv1, const float* __restrict__ Wv2,
    const float* __restrict__ Wl1, const float* __restrict__ Wl2,
    ushort* __restrict__ Wf1b, ushort* __restrict__ Wf2b,
    ushort* __restrict__ Wv1b, ushort* __restrict__ Wv2b,
    ushort* __restrict__ Wl1b, ushort* __restrict__ Wl2b)
{
  const long total = 147456 + 1179648 + 100864;
  long stride = (long)gridDim.x * blockDim.x;
  for (long i = (long)blockIdx.x * blockDim.x + threadIdx.x; i < total; i += stride) {
    if (i < 147456) {
      long j = i;
      if (j < 73728) Wf1b[j] = f2bf(Wf1[j]);
      else Wf2b[j - 73728] = f2bf(Wf2[j - 73728]);
    } else if (i < 147456 + 1179648) {
      long j = i - 147456;
      if (j < 589824) Wv1b[j] = f2bf(Wv1[j]);
      else Wv2b[j - 589824] = f2bf(Wv2[j - 589824]);
    } else {
      long j = i - 147456 - 1179648;
      int w2 = j >= 50432;
      if (w2) j -= 50432;
      int r = (int)(j >> 8), cc = (int)(j & 255);
      const float* s = w2 ? Wl2 : Wl1;
      ushort* d = w2 ? Wl2b : Wl1b;
      d[j] = (cc < 197) ? f2bf(s[(long)r * 197 + cc]) : (ushort)0;
    }
  }
}

__global__ __launch_bounds__(256) void conv_xy(const float* __restrict__ x,
                                               const float* __restrict__ y,
                                               ushort* __restrict__ xb,
                                               ushort* __restrict__ yb, long n8) {
  long i = (long)blockIdx.x * blockDim.x + threadIdx.x;
  long stride = (long)gridDim.x * blockDim.x;
  for (; i < 2 * n8; i += stride) {
    const float* s = (i < n8) ? x : y;
    ushort* d = (i < n8) ? xb : yb;
    long j = (i < n8) ? i : i - n8;
    float4 a = ((const float4*)s)[2 * j];
    float4 b = ((const float4*)s)[2 * j + 1];
    ushort8 o;
    o[0] = f2bf(a.x); o[1] = f2bf(a.y); o[2] = f2bf(a.z); o[3] = f2bf(a.w);
    o[4] = f2bf(b.x); o[5] = f2bf(b.y); o[6] = f2bf(b.z); o[7] = f2bf(b.w);
    *(ushort8*)&d[j * 8] = o;
  }
}

// ---------------- launcher ---------------------------------------------------
extern "C" void kernel_launch(void* const* d_in, const int* in_sizes, int n_in,
                              void* d_out, int out_size, void* d_ws, size_t ws_size,
                              hipStream_t stream) {
  const float* x   = (const float*)d_in[0];
  const float* y   = (const float*)d_in[1];
  const float* Wk1 = (const float*)d_in[2];
  const float* bk1 = (const float*)d_in[3];
  const float* Wk2 = (const float*)d_in[4];
  const float* bk2 = (const float*)d_in[5];
  const float* Wks = (const float*)d_in[6];
  const float* bks = (const float*)d_in[7];
  const float* Wl1 = (const float*)d_in[8];
  const float* bl1 = (const float*)d_in[9];
  const float* Wl2 = (const float*)d_in[10];
  const float* bl2 = (const float*)d_in[11];
  const float* Wv1 = (const float*)d_in[12];
  const float* bv1 = (const float*)d_in[13];
  const float* Wv2 = (const float*)d_in[14];
  const float* bv2 = (const float*)d_in[15];
  const float* gamma1 = (const float*)d_in[16];
  const float* gamma2 = (const float*)d_in[17];
  float* out = (float*)d_out;

  const int B = 256, L = 197, D = 768;
  const long LD = (long)L * D;     // 151296

  const size_t staticBytes = 3446784;
  const size_t perB = 605184 + 75648 + 100864 + 201728 + 201728;  // 1185152
  int Bc = 256;
  while (Bc > 8 && staticBytes + (size_t)Bc * perB > ws_size) Bc >>= 1;

  char* p = (char*)d_ws;
  auto carve = [&](size_t bytes) { char* r = p; p += bytes; return r; };
  float*  Wf1   = (float*)carve(73728 * 4);
  float*  Wf2   = (float*)carve(73728 * 4);
  float*  bf1   = (float*)carve(512);
  float*  bf2   = (float*)carve(512);
  ushort* Wv1b  = (ushort*)carve(589824 * 2);
  ushort* Wv2b  = (ushort*)carve(589824 * 2);
  ushort* Wf1b  = (ushort*)carve(73728 * 2);
  ushort* Wf2b  = (ushort*)carve(73728 * 2);
  ushort* Wl1b  = (ushort*)carve(50432 * 2);
  ushort* Wl2b  = (ushort*)carve(50432 * 2);
  ushort* xb    = (ushort*)carve((size_t)Bc * LD * 2);
  ushort* yb    = (ushort*)carve((size_t)Bc * LD * 2);
  ushort* k1    = (ushort*)carve((size_t)Bc * 18912 * 2);
  ushort* k2    = (ushort*)carve((size_t)Bc * 18912 * 2);
  ushort* EA1   = (ushort*)carve((size_t)Bc * 25216 * 2);
  ushort* EA2   = (ushort*)carve((size_t)Bc * 25216 * 2);
  ushort* Eb    = (ushort*)carve((size_t)Bc * 50432 * 2);
  ushort* ETbuf = (ushort*)carve((size_t)Bc * 50432 * 2);
  ushort* a1    = (ushort*)carve((size_t)Bc * 50432 * 2);
  ushort* a2    = (ushort*)carve((size_t)Bc * 50432 * 2);

  dim3 blk(256);

  gemm_generic<<<dim3(12, 2, 2), blk, 0, stream>>>(Wks, Wk1, Wk2, Wf1, Wf2,
      96, 768, 96, 96, 1, 1, 768, 768);
  fuse_bias2<<<1, 192, 0, stream>>>(Wks, bk1, bk2, bks, bf1, bf2);
  conv_weights<<<dim3(1024), blk, 0, stream>>>(Wf1, Wf2, Wv1, Wv2, Wl1, Wl2,
      Wf1b, Wf2b, Wv1b, Wv2b, Wl1b, Wl2b);

  for (int c0 = 0; c0 < B; c0 += Bc) {
    const float* xc = x + (long)c0 * LD;
    const float* yc = y + (long)c0 * LD;
    const int Mr = Bc * L;
    const int gym = (Mr + 127) / 128;

    conv_xy<<<dim3(2048), blk, 0, stream>>>(xc, yc, xb, yb, (long)Bc * LD / 8);

    mfma_gemm<<<dim3(1, gym, 2), blk, 0, stream>>>(xb, yb, Wf1b, Wf2b, bf1, bf2,
        k1, k2, Mr, 96, 768, 768, 768, 96);

    transpose_k<<<dim3(7, 4, 2 * Bc), blk, 0, stream>>>(k1, k2, EA1, EA2, Bc);

    energy_mfma<<<dim3(2, 2, Bc), blk, 0, stream>>>(EA1, EA2, Eb, ETbuf);

    att_gemm<<<dim3(4, Bc, 2), blk, 0, stream>>>(Wl1b, Wl2b, Eb, ETbuf,
        bl1, bl2, a1, a2);

    vfused_gemm<<<dim3(2 * 12 * Bc), blk, 0, stream>>>(
        Wv2b, Wv1b, yb, xb, bv2, bv1, a1, a2, xb, yb, gamma1, gamma2,
        out + (long)c0 * LD, out + (long)B * LD + (long)c0 * LD, Bc);
  }
}